// Round 11
// baseline (398.452 us; speedup 1.0000x reference)
//
#include <hip/hip_runtime.h>
#include <stdint.h>

#define PN 8192
#define SN 8192
#define KNB 16
#define SUBS 4                 // threshold subsample stride -> 2048 candidates
#define NCH1 8
#define CHUNK1 256             // subsample candidates per chunk
#define NCOL 8
#define COLCH (PN / NCOL)      // 1024 candidates per collect chunk
#define SEGCAP 32              // per-(sample,chunk) survivors: lambda=8, P(>32)~2e-12
#define MARGIN 1.0e-3f
#define NRCH 8
#define RCH (PN / NRCH)        // 1024

#define KEY_SENTINEL ((long long)0x8000000000000000ULL)
#define PD_SCALE 2199023255552.0   // 2^41: dd<1024 -> |scaled|<2^51; <<13 fits i64

// ---------------- helpers: branch-free sorted-16 maintenance ----------------
__device__ __forceinline__ void bitonic_sort16(float* b) {
#pragma unroll
    for (int k = 2; k <= 16; k <<= 1) {
#pragma unroll
        for (int j = k >> 1; j > 0; j >>= 1) {
#pragma unroll
            for (int i = 0; i < 16; ++i) {
                int l = i ^ j;
                if (l > i) {
                    float lo = fminf(b[i], b[l]), hi = fmaxf(b[i], b[l]);
                    bool up = ((i & k) == 0);
                    b[i] = up ? lo : hi;
                    b[l] = up ? hi : lo;
                }
            }
        }
    }
}
// r, b ascending sorted-16 -> r = lowest 16 of union, ascending.
__device__ __forceinline__ void merge16(float* r, const float* b) {
    float t[16];
#pragma unroll
    for (int i = 0; i < 16; ++i) t[i] = fminf(r[i], b[15 - i]);   // bitonic
#pragma unroll
    for (int j = 8; j > 0; j >>= 1) {
#pragma unroll
        for (int i = 0; i < 16; ++i) {
            int l = i ^ j;
            if (l > i) {
                float lo = fminf(t[i], t[l]), hi = fmaxf(t[i], t[l]);
                t[i] = lo; t[l] = hi;
            }
        }
    }
#pragma unroll
    for (int i = 0; i < 16; ++i) r[i] = t[i];
}

// ---------------- kernel 0: pack points (x,y,z,0) ----------------
__global__ void pack_pts_kernel(const float* __restrict__ x, float4* __restrict__ pts) {
    int i = blockIdx.x * 256 + threadIdx.x;           // 0 .. 2*PN-1
    int b = i >> 13, p = i & (PN - 1);
    const float* xb = x + (size_t)b * 4 * PN;
    pts[i] = make_float4(xb[p], xb[PN + p], xb[2 * PN + p], 0.f);
}

// ---------------- argsort stage A: partial rank counts (rank-by-counting) ----------------
__global__ __launch_bounds__(256) void rank_count_kernel(const float* __restrict__ rnd,
        unsigned short* __restrict__ rcnt) {
    __shared__ unsigned long long lk[RCH];            // 8 KB
    const int chunk = blockIdx.x, sg = blockIdx.y, b = blockIdx.z;
    const unsigned int* rb = (const unsigned int*)rnd + b * PN;   // [0,1) floats: bits order-preserving
    const int cbase = chunk * RCH;
    for (int c = threadIdx.x; c < RCH; c += 256) {
        int j = cbase + c;
        lk[c] = ((unsigned long long)rb[j] << 13) | (unsigned)j;
    }
    __syncthreads();
    const int i = sg * 256 + threadIdx.x;
    const unsigned long long ki = ((unsigned long long)rb[i] << 13) | (unsigned)i;
    int cnt = 0;
#pragma unroll 8
    for (int c = 0; c < RCH; ++c) cnt += (lk[c] < ki) ? 1 : 0;
    rcnt[(((size_t)(b * NRCH + chunk)) << 13) + i] = (unsigned short)cnt;
}

// ---------------- argsort stage B: sum partials, scatter perm[rank] = i ----------------
__global__ void rank_scatter_kernel(const unsigned short* __restrict__ rcnt,
                                    int* __restrict__ perm) {
    int t = blockIdx.x * 256 + threadIdx.x;           // 0 .. 2*PN-1
    int b = t >> 13, i = t & (PN - 1);
    int rank = 0;
#pragma unroll
    for (int ch = 0; ch < NRCH; ++ch)
        rank += rcnt[(((size_t)(b * NRCH + ch)) << 13) + i];
    perm[b * PN + rank] = i;
}

// ---------------- K1: per-(sample, subsample-chunk) sorted f32 top-16 distances ----------------
// Candidate stream is wave-uniform -> read straight from global (scalar-load path),
// no LDS staging. Stride-4 SUBSAMPLE: subset's 16th order stat >= true d16.
__global__ __launch_bounds__(256) void knn_val16_kernel(const float4* __restrict__ pts,
        const int* __restrict__ perm, float* __restrict__ vv) {
    const int chunk = blockIdx.x, sg = blockIdx.y, b = blockIdx.z;
    const float4* pb = pts + b * PN;
    const int pbase = chunk * CHUNK1;
    const int s = sg * 256 + threadIdx.x;
    const float4 qp = pb[perm[b * PN + s]];
    float r[16];
#pragma unroll
    for (int i = 0; i < 16; ++i) r[i] = 3.0e38f;
    for (int t = 0; t < CHUNK1; t += 16) {
        float bv[16];
#pragma unroll
        for (int u = 0; u < 16; ++u) {
            float4 pp = pb[SUBS * (pbase + t + u)];   // uniform addr -> s_load
            float dx = qp.x - pp.x, dy = qp.y - pp.y, dz = qp.z - pp.z;
            bv[u] = dx * dx + dy * dy + dz * dz;
        }
        bitonic_sort16(bv);
        merge16(r, bv);
    }
    float* ov = vv + ((size_t)(b * NCH1 + chunk) * 16) * SN + s;
#pragma unroll
    for (int i = 0; i < 16; ++i) ov[(size_t)i * SN] = r[i];
}

// ---------------- K1.5: merge 8 sorted chunk value-lists -> subsample d16 -> thr ----------------
__global__ void knn_thr_kernel(const float* __restrict__ vv, float* __restrict__ thrbuf) {
    int t = blockIdx.x * 256 + threadIdx.x;           // 0 .. 2*SN-1
    int b = t >> 13, s = t & (SN - 1);
    float r[16], bl[16];
    const float* v0 = vv + ((size_t)(b * NCH1) * 16) * SN + s;
#pragma unroll
    for (int i = 0; i < 16; ++i) r[i] = v0[(size_t)i * SN];
    for (int ch = 1; ch < NCH1; ++ch) {
        const float* vc = vv + ((size_t)(b * NCH1 + ch) * 16) * SN + s;
#pragma unroll
        for (int i = 0; i < 16; ++i) bl[i] = vc[(size_t)i * SN];
        merge16(r, bl);
    }
    thrbuf[b * SN + s] = r[15] + MARGIN;              // >= true global d16 (subset bound)
}

// ---------------- K2: collect survivors into PRIVATE per-(sample,chunk) segments ----------------
// Wave-uniform candidate reads straight from global (scalar path, zero LDS).
// Thread owns (sample, chunk): sole writer of its segment/count -> no atomics,
// no init, fully deterministic.
__global__ __launch_bounds__(256) void knn_collect_kernel(const float4* __restrict__ pts,
        const int* __restrict__ perm, const float* __restrict__ thrbuf,
        unsigned short* __restrict__ segcnt, unsigned short* __restrict__ segIdx) {
    const int chunk = blockIdx.x, sg = blockIdx.y, b = blockIdx.z;
    const float4* pb = pts + b * PN;
    const int pbase = chunk * COLCH;
    const int s = sg * 256 + threadIdx.x;
    const int bs = b * SN + s;
    const float4 qp = pb[perm[bs]];
    const float thr = thrbuf[bs];
    unsigned short* seg = segIdx + ((size_t)bs * NCOL + chunk) * SEGCAP;
    int cnt = 0;
#pragma unroll 4
    for (int c = 0; c < COLCH; ++c) {
        float4 pp = pb[pbase + c];                    // uniform addr -> s_load
        float dx = qp.x - pp.x, dy = qp.y - pp.y, dz = qp.z - pp.z;
        float dd = dx * dx;
        dd += dy * dy;
        dd += dz * dz;
        if (dd < thr) {
            if (cnt < SEGCAP) seg[cnt] = (unsigned short)(pbase + c);
            ++cnt;
        }
    }
    segcnt[(size_t)bs * NCOL + chunk] = (unsigned short)cnt;
}

// ---------------- K3: exact f64 top-16 over segment survivors -> knn[b][rank][s] ----------------
// Fixed chunk order + order-invariant full-key sort -> deterministic. Any segment
// overflow (P ~ 2e-12) triggers a deterministic full-scan fallback.
__global__ void knn_exact_kernel(const float4* __restrict__ pts, const int* __restrict__ perm,
        const unsigned short* __restrict__ segcnt, const unsigned short* __restrict__ segIdx,
        int* __restrict__ knn) {
    int t = blockIdx.x * 256 + threadIdx.x;           // 0 .. 2*SN-1
    int b = t >> 13, s = t & (SN - 1);
    const int bs = b * SN + s;
    const float4* pb = pts + b * PN;
    const float4 qp = pb[perm[bs]];
    const double qx = qp.x, qy = qp.y, qz = qp.z;
    long long kv[16];
#pragma unroll
    for (int i = 0; i < 16; ++i) kv[i] = KEY_SENTINEL;
    int ns[NCOL];
    bool ovf = false;
#pragma unroll
    for (int ch = 0; ch < NCOL; ++ch) {
        ns[ch] = segcnt[(size_t)bs * NCOL + ch];
        ovf |= (ns[ch] > SEGCAP);
    }
    if (!ovf) {
        const unsigned short* base = segIdx + (size_t)bs * (NCOL * SEGCAP);
        for (int ch = 0; ch < NCOL; ++ch) {
            const unsigned short* seg = base + ch * SEGCAP;
            const int n = ns[ch];
            for (int u = 0; u < n; ++u) {
                int c = seg[u];
                float4 pp = pb[c];
                double dx = qx - (double)pp.x;
                double dy = qy - (double)pp.y;
                double dz = qz - (double)pp.z;
                double dd = dx * dx + dy * dy + dz * dz;
                long long sc = (long long)floor(-dd * PD_SCALE);
                long long kk = (sc << 13) | (long long)(8191 - c);
                if (kk > kv[15]) {
#pragma unroll
                    for (int i = 15; i > 0; --i) {
                        bool sh = kk > kv[i - 1];
                        kv[i] = sh ? kv[i - 1] : ((kk > kv[i]) ? kk : kv[i]);
                    }
                    if (kk > kv[0]) kv[0] = kk;
                }
            }
        }
    } else {
        for (int c = 0; c < PN; ++c) {
            float4 pp = pb[c];
            double dx = qx - (double)pp.x;
            double dy = qy - (double)pp.y;
            double dz = qz - (double)pp.z;
            double dd = dx * dx + dy * dy + dz * dz;
            long long sc = (long long)floor(-dd * PD_SCALE);
            long long kk = (sc << 13) | (long long)(8191 - c);
            if (kk > kv[15]) {
#pragma unroll
                for (int i = 15; i > 0; --i) {
                    bool sh = kk > kv[i - 1];
                    kv[i] = sh ? kv[i - 1] : ((kk > kv[i]) ? kk : kv[i]);
                }
                if (kk > kv[0]) kv[0] = kk;
            }
        }
    }
    int* ob = knn + (size_t)b * (SN * KNB);
#pragma unroll
    for (int r = 0; r < KNB; ++r)
        ob[(size_t)r * SN + s] = 8191 - (int)(kv[r] & 8191);
}

// ---------------- kernel 4: GroupNorm statistics ----------------
__global__ __launch_bounds__(256) void stats_kernel(const float* __restrict__ x,
        const int* __restrict__ knn, const float* __restrict__ w_pe,
        const float* __restrict__ w_conv, float* __restrict__ wavepart) {
    const int blk = blockIdx.x;                       // 0..255
    const int b = blockIdx.y;
    const int w = threadIdx.x >> 6, l = threadIdx.x & 63;
    float wr[10];
#pragma unroll
    for (int c = 0; c < 10; ++c) wr[c] = 0.f;
    if (l < 32) {
#pragma unroll
        for (int c = 0; c < 4; ++c) wr[c] = w_conv[l * 4 + c];
    } else {
#pragma unroll
        for (int c = 0; c < 10; ++c) wr[c] = w_pe[(l - 32) * 10 + c];
    }
    const float* xb = x + (size_t)b * 4 * PN;
    const int* kb = knn + (size_t)b * (SN * KNB);
    float s1 = 0.f, s2 = 0.f;
    const int nbase = blk * 512 + w * 128;
#pragma unroll 2
    for (int it = 0; it < 128; ++it) {
        int n = nbase + it;
        int i  = kb[n];
        int i0 = kb[n & ~15];
        float xa0 = xb[i], xa1 = xb[PN + i], xa2 = xb[2 * PN + i], xa3 = xb[3 * PN + i];
        float xc0 = xb[i0], xc1 = xb[PN + i0], xc2 = xb[2 * PN + i0];
        float d0 = xa0 - xc0, d1 = xa1 - xc1, d2 = xa2 - xc2;
        float dd = d0 * d0; dd += d1 * d1; dd += d2 * d2;
        float temp = sqrtf(fmaxf(dd, 1e-12f));
        float r;
        if (l < 32) {
            r = wr[0] * xa0 + wr[1] * xa1 + wr[2] * xa2 + wr[3] * xa3;
        } else {
            r = wr[0] * xa0 + wr[1] * xa1 + wr[2] * xa2
              + wr[3] * xc0 + wr[4] * xc1 + wr[5] * xc2
              + wr[6] * d0 + wr[7] * d1 + wr[8] * d2 + wr[9] * temp;
        }
        s1 += r;
        s2 += r * r;
    }
    const int wslot = blk * 4 + w;                    // 0..1023
    wavepart[((size_t)b * 1024 + wslot) * 128 + l] = s1;
    wavepart[((size_t)b * 1024 + wslot) * 128 + 64 + l] = s2;
}

// ---------------- kernel 5: finalize stats -> per-channel scale/shift ----------------
__global__ void finalize_kernel(const float* __restrict__ wavepart,
        const float* __restrict__ g_pe, const float* __restrict__ b_pe,
        const float* __restrict__ g_conv, const float* __restrict__ b_conv,
        float* __restrict__ scsh) {
    const int t = threadIdx.x;                        // 0..255
    const int b = t >> 7, k = t & 127;
    float acc = 0.f;
    for (int w = 0; w < 1024; ++w) acc += wavepart[((size_t)b * 1024 + w) * 128 + k];
    __shared__ float sums[2][128];
    sums[b][k] = acc;
    __syncthreads();
    if (k < 64) {
        const float N = 131072.f;
        float mean = sums[b][k] / N;
        float var = sums[b][64 + k] / N - mean * mean;
        float rstd = 1.0f / sqrtf(var + 1e-5f);
        float gam = (k < 32) ? g_conv[k] : g_pe[k - 32];
        float bet = (k < 32) ? b_conv[k] : b_pe[k - 32];
        float sc = gam * rstd;
        scsh[(b * 64 + k) * 2 + 0] = sc;
        scsh[(b * 64 + k) * 2 + 1] = bet - mean * sc;
    }
}

// ---------------- kernel 6: fused feature/attention/output ----------------
__global__ __launch_bounds__(256) void fused_main_kernel(
        const float* __restrict__ x, const int* __restrict__ knn,
        const float* __restrict__ w_pe, const float* __restrict__ w_conv,
        const float* __restrict__ w_att1, const float* __restrict__ w_att2,
        const float* __restrict__ w_b1, const float* __restrict__ w_b2,
        const float* __restrict__ scsh, float* __restrict__ out) {
    __shared__ float wb1T[64 * 64];                   // [c][o]
    __shared__ float wb2T[4 * 64];                    // [c][o]
    for (int i = threadIdx.x; i < 64 * 64; i += 256) wb1T[(i & 63) * 64 + (i >> 6)] = w_b1[i];
    { int i = threadIdx.x; wb2T[(i & 3) * 64 + (i >> 2)] = w_b2[i]; }
    __syncthreads();
    const int gidx = blockIdx.x;                      // 0..1023
    const int b = gidx >> 9;
    const int sb = (gidx & 511) << 4;
    const int l = threadIdx.x & 63;
    const int w = threadIdx.x >> 6;
    const int g = l >> 4, j = l & 15;
    const int s = sb + (w << 2) + g;
    const int srcl = g << 4;
    const float* xb = x + (size_t)b * 4 * PN;
    const int i1 = knn[(size_t)b * (SN * KNB) + (size_t)s * KNB + j];
    float xa0 = xb[i1], xa1 = xb[PN + i1], xa2 = xb[2 * PN + i1], xa3 = xb[3 * PN + i1];
    float xc0 = __shfl(xa0, srcl), xc1 = __shfl(xa1, srcl);
    float xc2 = __shfl(xa2, srcl), xc3 = __shfl(xa3, srcl);
    float d0 = xa0 - xc0, d1 = xa1 - xc1, d2 = xa2 - xc2;
    float dd = d0 * d0; dd += d1 * d1; dd += d2 * d2;
    float temp = sqrtf(fmaxf(dd, 1e-12f));
    float pem[10] = {xa0, xa1, xa2, xc0, xc1, xc2, d0, d1, d2, temp};
    float f[64];
    const float* ssb = scsh + b * 128;
#pragma unroll
    for (int o = 0; o < 32; ++o) {
        float r = w_conv[o * 4 + 0] * xa0;
        r += w_conv[o * 4 + 1] * xa1;
        r += w_conv[o * 4 + 2] * xa2;
        r += w_conv[o * 4 + 3] * xa3;
        r = r * ssb[o * 2 + 0] + ssb[o * 2 + 1];
        f[o] = (r >= 0.f) ? r : 0.2f * r;
    }
#pragma unroll
    for (int o = 0; o < 32; ++o) {
        float r = 0.f;
#pragma unroll
        for (int c = 0; c < 10; ++c) r += w_pe[o * 10 + c] * pem[c];
        r = r * ssb[(32 + o) * 2 + 0] + ssb[(32 + o) * 2 + 1];
        f[32 + o] = (r >= 0.f) ? r : 0.2f * r;
    }
    float logit = 0.f;
#pragma unroll 2
    for (int o = 0; o < 32; ++o) {
        float a = 0.f;
#pragma unroll
        for (int c = 0; c < 64; ++c) a += w_att1[o * 64 + c] * f[c];
        a = (a >= 0.f) ? a : 0.2f * a;
        logit += w_att2[o] * a;
    }
    float mx = logit;
    mx = fmaxf(mx, __shfl_xor(mx, 1));
    mx = fmaxf(mx, __shfl_xor(mx, 2));
    mx = fmaxf(mx, __shfl_xor(mx, 4));
    mx = fmaxf(mx, __shfl_xor(mx, 8));
    float e = expf(logit - mx);
    float se = e;
    se += __shfl_xor(se, 1);
    se += __shfl_xor(se, 2);
    se += __shfl_xor(se, 4);
    se += __shfl_xor(se, 8);
    float att = e / se;
#pragma unroll
    for (int c = 0; c < 64; ++c) {
        float v = f[c] * att;
        v += __shfl_xor(v, 1);
        v += __shfl_xor(v, 2);
        v += __shfl_xor(v, 4);
        v += __shfl_xor(v, 8);
        f[c] = v;
    }
    float o0 = 0.f, o1 = 0.f, o2 = 0.f, o3 = 0.f;
#pragma unroll
    for (int c = 0; c < 64; ++c) {
        float4 wv = *reinterpret_cast<const float4*>(&wb1T[c * 64 + 4 * j]);
        o0 += wv.x * f[c]; o1 += wv.y * f[c]; o2 += wv.z * f[c]; o3 += wv.w * f[c];
    }
    {
        float4 wv = *reinterpret_cast<const float4*>(&wb2T[0 * 64 + 4 * j]);
        o0 += wv.x * xc0; o1 += wv.y * xc0; o2 += wv.z * xc0; o3 += wv.w * xc0;
        wv = *reinterpret_cast<const float4*>(&wb2T[1 * 64 + 4 * j]);
        o0 += wv.x * xc1; o1 += wv.y * xc1; o2 += wv.z * xc1; o3 += wv.w * xc1;
        wv = *reinterpret_cast<const float4*>(&wb2T[2 * 64 + 4 * j]);
        o0 += wv.x * xc2; o1 += wv.y * xc2; o2 += wv.z * xc2; o3 += wv.w * xc2;
        wv = *reinterpret_cast<const float4*>(&wb2T[3 * 64 + 4 * j]);
        o0 += wv.x * xc3; o1 += wv.y * xc3; o2 += wv.z * xc3; o3 += wv.w * xc3;
    }
    o0 = (o0 >= 0.f) ? o0 : 0.1f * o0;
    o1 = (o1 >= 0.f) ? o1 : 0.1f * o1;
    o2 = (o2 >= 0.f) ? o2 : 0.1f * o2;
    o3 = (o3 >= 0.f) ? o3 : 0.1f * o3;
    float* ob = out + (size_t)b * 67 * SN;
    const int oc = 3 + 4 * j;
    ob[(size_t)(oc + 0) * SN + s] = o0;
    ob[(size_t)(oc + 1) * SN + s] = o1;
    ob[(size_t)(oc + 2) * SN + s] = o2;
    ob[(size_t)(oc + 3) * SN + s] = o3;
    if (j < 3) ob[(size_t)j * SN + s] = (j == 0) ? xc0 : ((j == 1) ? xc1 : xc2);
}

extern "C" void kernel_launch(void* const* d_in, const int* in_sizes, int n_in,
                              void* d_out, int out_size, void* d_ws, size_t ws_size,
                              hipStream_t stream) {
    (void)in_sizes; (void)n_in; (void)out_size; (void)ws_size;
    const float* x      = (const float*)d_in[0];
    const float* rnd    = (const float*)d_in[1];
    const float* w_pe   = (const float*)d_in[2];
    const float* g_pe   = (const float*)d_in[3];
    const float* b_pe   = (const float*)d_in[4];
    const float* w_conv = (const float*)d_in[5];
    const float* g_conv = (const float*)d_in[6];
    const float* b_conv = (const float*)d_in[7];
    const float* w_att1 = (const float*)d_in[8];
    const float* w_att2 = (const float*)d_in[9];
    const float* w_b1   = (const float*)d_in[10];
    const float* w_b2   = (const float*)d_in[11];
    float* out = (float*)d_out;
    char* ws = (char*)d_ws;
    // workspace carve-up (bytes), peak ~10.09 MB (< proven 10.81 MB).
    // Region A [327680, 8716288) = 8 MB, time-shared sequentially:
    //   rcnt (256K; rank_count->scatter) -> vv (8MB; K1->K1.5)
    //   -> segIdx (8MB exactly; collect->exact) -> wavept (1MB; stats->finalize)
    float4*         pts    = (float4*)        (ws + 0);          //   262,144
    int*            perm   = (int*)           (ws + 262144);     //    65,536
    unsigned short* rcnt   = (unsigned short*)(ws + 327680);     //   262,144 (A)
    float*          vv     = (float*)         (ws + 327680);     // 8,388,608 (A)
    unsigned short* segIdx = (unsigned short*)(ws + 327680);     // 8,388,608 (A) 16384*8*32*2
    float*          wavept = (float*)         (ws + 327680);     // 1,048,576 (A)
    float*          thrbuf = (float*)         (ws + 8716288);    //    65,536
    unsigned short* segcnt = (unsigned short*)(ws + 8781824);    //   262,144
    int*            knn    = (int*)           (ws + 9043968);    // 1,048,576
    float*          scsh   = (float*)         (ws + 10092544);   //     1,024

    pack_pts_kernel<<<64, 256, 0, stream>>>(x, pts);
    rank_count_kernel<<<dim3(NRCH, 32, 2), 256, 0, stream>>>(rnd, rcnt);
    rank_scatter_kernel<<<64, 256, 0, stream>>>(rcnt, perm);
    knn_val16_kernel<<<dim3(NCH1, 32, 2), 256, 0, stream>>>(pts, perm, vv);
    knn_thr_kernel<<<64, 256, 0, stream>>>(vv, thrbuf);
    knn_collect_kernel<<<dim3(NCOL, 32, 2), 256, 0, stream>>>(pts, perm, thrbuf, segcnt, segIdx);
    knn_exact_kernel<<<64, 256, 0, stream>>>(pts, perm, segcnt, segIdx, knn);
    stats_kernel<<<dim3(256, 2), 256, 0, stream>>>(x, knn, w_pe, w_conv, wavept);
    finalize_kernel<<<1, 256, 0, stream>>>(wavept, g_pe, b_pe, g_conv, b_conv, scsh);
    fused_main_kernel<<<1024, 256, 0, stream>>>(x, knn, w_pe, w_conv, w_att1, w_att2,
                                                w_b1, w_b2, scsh, out);
}

// Round 12
// 395.224 us; speedup vs baseline: 1.0082x; 1.0082x over previous
//
#include <hip/hip_runtime.h>
#include <stdint.h>

#define PN 8192
#define SN 8192
#define KNB 16
#define SUBS 4                 // threshold subsample stride -> 2048 candidates
#define NCH1 8
#define CHUNK1 256             // subsample candidates per chunk
#define NCOL 8
#define COLCH (PN / NCOL)      // 1024 candidates per collect chunk
#define SEGCAP 32              // per-(sample,chunk) survivors: lambda=8, P(>32)~2e-12
#define MARGIN 1.0e-3f
#define NRCH 8
#define RCH (PN / NRCH)        // 1024

#define KEY_SENTINEL ((long long)0x8000000000000000ULL)
#define PD_SCALE 2199023255552.0   // 2^41: dd<1024 -> |scaled|<2^51; <<13 fits i64

// ---------------- helpers: branch-free sorted-16 maintenance ----------------
__device__ __forceinline__ void bitonic_sort16(float* b) {
#pragma unroll
    for (int k = 2; k <= 16; k <<= 1) {
#pragma unroll
        for (int j = k >> 1; j > 0; j >>= 1) {
#pragma unroll
            for (int i = 0; i < 16; ++i) {
                int l = i ^ j;
                if (l > i) {
                    float lo = fminf(b[i], b[l]), hi = fmaxf(b[i], b[l]);
                    bool up = ((i & k) == 0);
                    b[i] = up ? lo : hi;
                    b[l] = up ? hi : lo;
                }
            }
        }
    }
}
// r, b ascending sorted-16 -> r = lowest 16 of union, ascending.
__device__ __forceinline__ void merge16(float* r, const float* b) {
    float t[16];
#pragma unroll
    for (int i = 0; i < 16; ++i) t[i] = fminf(r[i], b[15 - i]);   // bitonic
#pragma unroll
    for (int j = 8; j > 0; j >>= 1) {
#pragma unroll
        for (int i = 0; i < 16; ++i) {
            int l = i ^ j;
            if (l > i) {
                float lo = fminf(t[i], t[l]), hi = fmaxf(t[i], t[l]);
                t[i] = lo; t[l] = hi;
            }
        }
    }
#pragma unroll
    for (int i = 0; i < 16; ++i) r[i] = t[i];
}

// ---------------- kernel 0: pack points (x,y,z,0) ----------------
__global__ void pack_pts_kernel(const float* __restrict__ x, float4* __restrict__ pts) {
    int i = blockIdx.x * 256 + threadIdx.x;           // 0 .. 2*PN-1
    int b = i >> 13, p = i & (PN - 1);
    const float* xb = x + (size_t)b * 4 * PN;
    pts[i] = make_float4(xb[p], xb[PN + p], xb[2 * PN + p], 0.f);
}

// ---------------- argsort stage A: partial rank counts (rank-by-counting) ----------------
__global__ __launch_bounds__(256) void rank_count_kernel(const float* __restrict__ rnd,
        unsigned short* __restrict__ rcnt) {
    __shared__ unsigned long long lk[RCH];            // 8 KB
    const int chunk = blockIdx.x, sg = blockIdx.y, b = blockIdx.z;
    const unsigned int* rb = (const unsigned int*)rnd + b * PN;   // [0,1) floats: bits order-preserving
    const int cbase = chunk * RCH;
    for (int c = threadIdx.x; c < RCH; c += 256) {
        int j = cbase + c;
        lk[c] = ((unsigned long long)rb[j] << 13) | (unsigned)j;
    }
    __syncthreads();
    const int i = sg * 256 + threadIdx.x;
    const unsigned long long ki = ((unsigned long long)rb[i] << 13) | (unsigned)i;
    int cnt = 0;
#pragma unroll 8
    for (int c = 0; c < RCH; ++c) cnt += (lk[c] < ki) ? 1 : 0;
    rcnt[(((size_t)(b * NRCH + chunk)) << 13) + i] = (unsigned short)cnt;
}

// ---------------- argsort stage B: sum partials, scatter perm[rank] = i ----------------
__global__ void rank_scatter_kernel(const unsigned short* __restrict__ rcnt,
                                    int* __restrict__ perm) {
    int t = blockIdx.x * 256 + threadIdx.x;           // 0 .. 2*PN-1
    int b = t >> 13, i = t & (PN - 1);
    int rank = 0;
#pragma unroll
    for (int ch = 0; ch < NRCH; ++ch)
        rank += rcnt[(((size_t)(b * NRCH + ch)) << 13) + i];
    perm[b * PN + rank] = i;
}

// ---------------- K1: per-(sample, subsample-chunk) sorted f32 top-16 distances ----------------
// Candidate stream is wave-uniform -> read straight from global (scalar-load path),
// no LDS staging. Stride-4 SUBSAMPLE: subset's 16th order stat >= true d16.
__global__ __launch_bounds__(256) void knn_val16_kernel(const float4* __restrict__ pts,
        const int* __restrict__ perm, float* __restrict__ vv) {
    const int chunk = blockIdx.x, sg = blockIdx.y, b = blockIdx.z;
    const float4* pb = pts + b * PN;
    const int pbase = chunk * CHUNK1;
    const int s = sg * 256 + threadIdx.x;
    const float4 qp = pb[perm[b * PN + s]];
    float r[16];
#pragma unroll
    for (int i = 0; i < 16; ++i) r[i] = 3.0e38f;
    for (int t = 0; t < CHUNK1; t += 16) {
        float bv[16];
#pragma unroll
        for (int u = 0; u < 16; ++u) {
            float4 pp = pb[SUBS * (pbase + t + u)];   // uniform addr -> s_load
            float dx = qp.x - pp.x, dy = qp.y - pp.y, dz = qp.z - pp.z;
            bv[u] = dx * dx + dy * dy + dz * dz;
        }
        bitonic_sort16(bv);
        merge16(r, bv);
    }
    float* ov = vv + ((size_t)(b * NCH1 + chunk) * 16) * SN + s;
#pragma unroll
    for (int i = 0; i < 16; ++i) ov[(size_t)i * SN] = r[i];
}

// ---------------- K1.5: merge 8 sorted chunk value-lists -> subsample d16 -> thr ----------------
__global__ void knn_thr_kernel(const float* __restrict__ vv, float* __restrict__ thrbuf) {
    int t = blockIdx.x * 256 + threadIdx.x;           // 0 .. 2*SN-1
    int b = t >> 13, s = t & (SN - 1);
    float r[16], bl[16];
    const float* v0 = vv + ((size_t)(b * NCH1) * 16) * SN + s;
#pragma unroll
    for (int i = 0; i < 16; ++i) r[i] = v0[(size_t)i * SN];
    for (int ch = 1; ch < NCH1; ++ch) {
        const float* vc = vv + ((size_t)(b * NCH1 + ch) * 16) * SN + s;
#pragma unroll
        for (int i = 0; i < 16; ++i) bl[i] = vc[(size_t)i * SN];
        merge16(r, bl);
    }
    thrbuf[b * SN + s] = r[15] + MARGIN;              // >= true global d16 (subset bound)
}

// ---------------- K2: collect survivors into PRIVATE per-(sample,chunk) segments ----------------
// Wave-uniform candidate reads straight from global (scalar path, zero LDS).
// Thread owns (sample, chunk): sole writer of its segment/count -> no atomics,
// no init, fully deterministic.
__global__ __launch_bounds__(256) void knn_collect_kernel(const float4* __restrict__ pts,
        const int* __restrict__ perm, const float* __restrict__ thrbuf,
        unsigned short* __restrict__ segcnt, unsigned short* __restrict__ segIdx) {
    const int chunk = blockIdx.x, sg = blockIdx.y, b = blockIdx.z;
    const float4* pb = pts + b * PN;
    const int pbase = chunk * COLCH;
    const int s = sg * 256 + threadIdx.x;
    const int bs = b * SN + s;
    const float4 qp = pb[perm[bs]];
    const float thr = thrbuf[bs];
    unsigned short* seg = segIdx + ((size_t)bs * NCOL + chunk) * SEGCAP;
    int cnt = 0;
#pragma unroll 4
    for (int c = 0; c < COLCH; ++c) {
        float4 pp = pb[pbase + c];                    // uniform addr -> s_load
        float dx = qp.x - pp.x, dy = qp.y - pp.y, dz = qp.z - pp.z;
        float dd = dx * dx;
        dd += dy * dy;
        dd += dz * dz;
        if (dd < thr) {
            if (cnt < SEGCAP) seg[cnt] = (unsigned short)(pbase + c);
            ++cnt;
        }
    }
    segcnt[(size_t)bs * NCOL + chunk] = (unsigned short)cnt;
}

// ---------------- K3: exact f64 top-16 over segment survivors -> knn[b][rank][s] ----------------
// Fixed chunk order + order-invariant full-key sort -> deterministic. Any segment
// overflow (P ~ 2e-12) triggers a deterministic full-scan fallback.
__global__ void knn_exact_kernel(const float4* __restrict__ pts, const int* __restrict__ perm,
        const unsigned short* __restrict__ segcnt, const unsigned short* __restrict__ segIdx,
        int* __restrict__ knn) {
    int t = blockIdx.x * 256 + threadIdx.x;           // 0 .. 2*SN-1
    int b = t >> 13, s = t & (SN - 1);
    const int bs = b * SN + s;
    const float4* pb = pts + b * PN;
    const float4 qp = pb[perm[bs]];
    const double qx = qp.x, qy = qp.y, qz = qp.z;
    long long kv[16];
#pragma unroll
    for (int i = 0; i < 16; ++i) kv[i] = KEY_SENTINEL;
    int ns[NCOL];
    bool ovf = false;
#pragma unroll
    for (int ch = 0; ch < NCOL; ++ch) {
        ns[ch] = segcnt[(size_t)bs * NCOL + ch];
        ovf |= (ns[ch] > SEGCAP);
    }
    if (!ovf) {
        const unsigned short* base = segIdx + (size_t)bs * (NCOL * SEGCAP);
        for (int ch = 0; ch < NCOL; ++ch) {
            const unsigned short* seg = base + ch * SEGCAP;
            const int n = ns[ch];
            for (int u = 0; u < n; ++u) {
                int c = seg[u];
                float4 pp = pb[c];
                double dx = qx - (double)pp.x;
                double dy = qy - (double)pp.y;
                double dz = qz - (double)pp.z;
                double dd = dx * dx + dy * dy + dz * dz;
                long long sc = (long long)floor(-dd * PD_SCALE);
                long long kk = (sc << 13) | (long long)(8191 - c);
                if (kk > kv[15]) {
#pragma unroll
                    for (int i = 15; i > 0; --i) {
                        bool sh = kk > kv[i - 1];
                        kv[i] = sh ? kv[i - 1] : ((kk > kv[i]) ? kk : kv[i]);
                    }
                    if (kk > kv[0]) kv[0] = kk;
                }
            }
        }
    } else {
        for (int c = 0; c < PN; ++c) {
            float4 pp = pb[c];
            double dx = qx - (double)pp.x;
            double dy = qy - (double)pp.y;
            double dz = qz - (double)pp.z;
            double dd = dx * dx + dy * dy + dz * dz;
            long long sc = (long long)floor(-dd * PD_SCALE);
            long long kk = (sc << 13) | (long long)(8191 - c);
            if (kk > kv[15]) {
#pragma unroll
                for (int i = 15; i > 0; --i) {
                    bool sh = kk > kv[i - 1];
                    kv[i] = sh ? kv[i - 1] : ((kk > kv[i]) ? kk : kv[i]);
                }
                if (kk > kv[0]) kv[0] = kk;
            }
        }
    }
    int* ob = knn + (size_t)b * (SN * KNB);
#pragma unroll
    for (int r = 0; r < KNB; ++r)
        ob[(size_t)r * SN + s] = 8191 - (int)(kv[r] & 8191);
}

// ---------------- kernel 4: GroupNorm statistics ----------------
__global__ __launch_bounds__(256) void stats_kernel(const float* __restrict__ x,
        const int* __restrict__ knn, const float* __restrict__ w_pe,
        const float* __restrict__ w_conv, float* __restrict__ wavepart) {
    const int blk = blockIdx.x;                       // 0..255
    const int b = blockIdx.y;
    const int w = threadIdx.x >> 6, l = threadIdx.x & 63;
    float wr[10];
#pragma unroll
    for (int c = 0; c < 10; ++c) wr[c] = 0.f;
    if (l < 32) {
#pragma unroll
        for (int c = 0; c < 4; ++c) wr[c] = w_conv[l * 4 + c];
    } else {
#pragma unroll
        for (int c = 0; c < 10; ++c) wr[c] = w_pe[(l - 32) * 10 + c];
    }
    const float* xb = x + (size_t)b * 4 * PN;
    const int* kb = knn + (size_t)b * (SN * KNB);
    float s1 = 0.f, s2 = 0.f;
    const int nbase = blk * 512 + w * 128;
#pragma unroll 2
    for (int it = 0; it < 128; ++it) {
        int n = nbase + it;
        int i  = kb[n];
        int i0 = kb[n & ~15];
        float xa0 = xb[i], xa1 = xb[PN + i], xa2 = xb[2 * PN + i], xa3 = xb[3 * PN + i];
        float xc0 = xb[i0], xc1 = xb[PN + i0], xc2 = xb[2 * PN + i0];
        float d0 = xa0 - xc0, d1 = xa1 - xc1, d2 = xa2 - xc2;
        float dd = d0 * d0; dd += d1 * d1; dd += d2 * d2;
        float temp = sqrtf(fmaxf(dd, 1e-12f));
        float r;
        if (l < 32) {
            r = wr[0] * xa0 + wr[1] * xa1 + wr[2] * xa2 + wr[3] * xa3;
        } else {
            r = wr[0] * xa0 + wr[1] * xa1 + wr[2] * xa2
              + wr[3] * xc0 + wr[4] * xc1 + wr[5] * xc2
              + wr[6] * d0 + wr[7] * d1 + wr[8] * d2 + wr[9] * temp;
        }
        s1 += r;
        s2 += r * r;
    }
    const int wslot = blk * 4 + w;                    // 0..1023
    wavepart[((size_t)b * 1024 + wslot) * 128 + l] = s1;
    wavepart[((size_t)b * 1024 + wslot) * 128 + 64 + l] = s2;
}

// ---------------- kernel 5: finalize stats -> per-channel scale/shift ----------------
__global__ void finalize_kernel(const float* __restrict__ wavepart,
        const float* __restrict__ g_pe, const float* __restrict__ b_pe,
        const float* __restrict__ g_conv, const float* __restrict__ b_conv,
        float* __restrict__ scsh) {
    const int t = threadIdx.x;                        // 0..255
    const int b = t >> 7, k = t & 127;
    float acc = 0.f;
    for (int w = 0; w < 1024; ++w) acc += wavepart[((size_t)b * 1024 + w) * 128 + k];
    __shared__ float sums[2][128];
    sums[b][k] = acc;
    __syncthreads();
    if (k < 64) {
        const float N = 131072.f;
        float mean = sums[b][k] / N;
        float var = sums[b][64 + k] / N - mean * mean;
        float rstd = 1.0f / sqrtf(var + 1e-5f);
        float gam = (k < 32) ? g_conv[k] : g_pe[k - 32];
        float bet = (k < 32) ? b_conv[k] : b_pe[k - 32];
        float sc = gam * rstd;
        scsh[(b * 64 + k) * 2 + 0] = sc;
        scsh[(b * 64 + k) * 2 + 1] = bet - mean * sc;
    }
}

// ---------------- kernel 6: fused feature/attention/output ----------------
__global__ __launch_bounds__(256) void fused_main_kernel(
        const float* __restrict__ x, const int* __restrict__ knn,
        const float* __restrict__ w_pe, const float* __restrict__ w_conv,
        const float* __restrict__ w_att1, const float* __restrict__ w_att2,
        const float* __restrict__ w_b1, const float* __restrict__ w_b2,
        const float* __restrict__ scsh, float* __restrict__ out) {
    __shared__ float wb1T[64 * 64];                   // [c][o]
    __shared__ float wb2T[4 * 64];                    // [c][o]
    for (int i = threadIdx.x; i < 64 * 64; i += 256) wb1T[(i & 63) * 64 + (i >> 6)] = w_b1[i];
    { int i = threadIdx.x; wb2T[(i & 3) * 64 + (i >> 2)] = w_b2[i]; }
    __syncthreads();
    const int gidx = blockIdx.x;                      // 0..1023
    const int b = gidx >> 9;
    const int sb = (gidx & 511) << 4;
    const int l = threadIdx.x & 63;
    const int w = threadIdx.x >> 6;
    const int g = l >> 4, j = l & 15;
    const int s = sb + (w << 2) + g;
    const int srcl = g << 4;
    const float* xb = x + (size_t)b * 4 * PN;
    const int i1 = knn[(size_t)b * (SN * KNB) + (size_t)s * KNB + j];
    float xa0 = xb[i1], xa1 = xb[PN + i1], xa2 = xb[2 * PN + i1], xa3 = xb[3 * PN + i1];
    float xc0 = __shfl(xa0, srcl), xc1 = __shfl(xa1, srcl);
    float xc2 = __shfl(xa2, srcl), xc3 = __shfl(xa3, srcl);
    float d0 = xa0 - xc0, d1 = xa1 - xc1, d2 = xa2 - xc2;
    float dd = d0 * d0; dd += d1 * d1; dd += d2 * d2;
    float temp = sqrtf(fmaxf(dd, 1e-12f));
    float pem[10] = {xa0, xa1, xa2, xc0, xc1, xc2, d0, d1, d2, temp};
    float f[64];
    const float* ssb = scsh + b * 128;
#pragma unroll
    for (int o = 0; o < 32; ++o) {
        float r = w_conv[o * 4 + 0] * xa0;
        r += w_conv[o * 4 + 1] * xa1;
        r += w_conv[o * 4 + 2] * xa2;
        r += w_conv[o * 4 + 3] * xa3;
        r = r * ssb[o * 2 + 0] + ssb[o * 2 + 1];
        f[o] = (r >= 0.f) ? r : 0.2f * r;
    }
#pragma unroll
    for (int o = 0; o < 32; ++o) {
        float r = 0.f;
#pragma unroll
        for (int c = 0; c < 10; ++c) r += w_pe[o * 10 + c] * pem[c];
        r = r * ssb[(32 + o) * 2 + 0] + ssb[(32 + o) * 2 + 1];
        f[32 + o] = (r >= 0.f) ? r : 0.2f * r;
    }
    float logit = 0.f;
#pragma unroll 2
    for (int o = 0; o < 32; ++o) {
        float a = 0.f;
#pragma unroll
        for (int c = 0; c < 64; ++c) a += w_att1[o * 64 + c] * f[c];
        a = (a >= 0.f) ? a : 0.2f * a;
        logit += w_att2[o] * a;
    }
    float mx = logit;
    mx = fmaxf(mx, __shfl_xor(mx, 1));
    mx = fmaxf(mx, __shfl_xor(mx, 2));
    mx = fmaxf(mx, __shfl_xor(mx, 4));
    mx = fmaxf(mx, __shfl_xor(mx, 8));
    float e = expf(logit - mx);
    float se = e;
    se += __shfl_xor(se, 1);
    se += __shfl_xor(se, 2);
    se += __shfl_xor(se, 4);
    se += __shfl_xor(se, 8);
    float att = e / se;
#pragma unroll
    for (int c = 0; c < 64; ++c) {
        float v = f[c] * att;
        v += __shfl_xor(v, 1);
        v += __shfl_xor(v, 2);
        v += __shfl_xor(v, 4);
        v += __shfl_xor(v, 8);
        f[c] = v;
    }
    float o0 = 0.f, o1 = 0.f, o2 = 0.f, o3 = 0.f;
#pragma unroll
    for (int c = 0; c < 64; ++c) {
        float4 wv = *reinterpret_cast<const float4*>(&wb1T[c * 64 + 4 * j]);
        o0 += wv.x * f[c]; o1 += wv.y * f[c]; o2 += wv.z * f[c]; o3 += wv.w * f[c];
    }
    {
        float4 wv = *reinterpret_cast<const float4*>(&wb2T[0 * 64 + 4 * j]);
        o0 += wv.x * xc0; o1 += wv.y * xc0; o2 += wv.z * xc0; o3 += wv.w * xc0;
        wv = *reinterpret_cast<const float4*>(&wb2T[1 * 64 + 4 * j]);
        o0 += wv.x * xc1; o1 += wv.y * xc1; o2 += wv.z * xc1; o3 += wv.w * xc1;
        wv = *reinterpret_cast<const float4*>(&wb2T[2 * 64 + 4 * j]);
        o0 += wv.x * xc2; o1 += wv.y * xc2; o2 += wv.z * xc2; o3 += wv.w * xc2;
        wv = *reinterpret_cast<const float4*>(&wb2T[3 * 64 + 4 * j]);
        o0 += wv.x * xc3; o1 += wv.y * xc3; o2 += wv.z * xc3; o3 += wv.w * xc3;
    }
    o0 = (o0 >= 0.f) ? o0 : 0.1f * o0;
    o1 = (o1 >= 0.f) ? o1 : 0.1f * o1;
    o2 = (o2 >= 0.f) ? o2 : 0.1f * o2;
    o3 = (o3 >= 0.f) ? o3 : 0.1f * o3;
    float* ob = out + (size_t)b * 67 * SN;
    const int oc = 3 + 4 * j;
    ob[(size_t)(oc + 0) * SN + s] = o0;
    ob[(size_t)(oc + 1) * SN + s] = o1;
    ob[(size_t)(oc + 2) * SN + s] = o2;
    ob[(size_t)(oc + 3) * SN + s] = o3;
    if (j < 3) ob[(size_t)j * SN + s] = (j == 0) ? xc0 : ((j == 1) ? xc1 : xc2);
}

extern "C" void kernel_launch(void* const* d_in, const int* in_sizes, int n_in,
                              void* d_out, int out_size, void* d_ws, size_t ws_size,
                              hipStream_t stream) {
    (void)in_sizes; (void)n_in; (void)out_size; (void)ws_size;
    const float* x      = (const float*)d_in[0];
    const float* rnd    = (const float*)d_in[1];
    const float* w_pe   = (const float*)d_in[2];
    const float* g_pe   = (const float*)d_in[3];
    const float* b_pe   = (const float*)d_in[4];
    const float* w_conv = (const float*)d_in[5];
    const float* g_conv = (const float*)d_in[6];
    const float* b_conv = (const float*)d_in[7];
    const float* w_att1 = (const float*)d_in[8];
    const float* w_att2 = (const float*)d_in[9];
    const float* w_b1   = (const float*)d_in[10];
    const float* w_b2   = (const float*)d_in[11];
    float* out = (float*)d_out;
    char* ws = (char*)d_ws;
    // workspace carve-up (bytes), peak ~10.09 MB (< proven 10.81 MB).
    // Region A [327680, 8716288) = 8 MB, time-shared sequentially:
    //   rcnt (256K; rank_count->scatter) -> vv (8MB; K1->K1.5)
    //   -> segIdx (8MB exactly; collect->exact) -> wavept (1MB; stats->finalize)
    float4*         pts    = (float4*)        (ws + 0);          //   262,144
    int*            perm   = (int*)           (ws + 262144);     //    65,536
    unsigned short* rcnt   = (unsigned short*)(ws + 327680);     //   262,144 (A)
    float*          vv     = (float*)         (ws + 327680);     // 8,388,608 (A)
    unsigned short* segIdx = (unsigned short*)(ws + 327680);     // 8,388,608 (A) 16384*8*32*2
    float*          wavept = (float*)         (ws + 327680);     // 1,048,576 (A)
    float*          thrbuf = (float*)         (ws + 8716288);    //    65,536
    unsigned short* segcnt = (unsigned short*)(ws + 8781824);    //   262,144
    int*            knn    = (int*)           (ws + 9043968);    // 1,048,576
    float*          scsh   = (float*)         (ws + 10092544);   //     1,024

    pack_pts_kernel<<<64, 256, 0, stream>>>(x, pts);
    rank_count_kernel<<<dim3(NRCH, 32, 2), 256, 0, stream>>>(rnd, rcnt);
    rank_scatter_kernel<<<64, 256, 0, stream>>>(rcnt, perm);
    knn_val16_kernel<<<dim3(NCH1, 32, 2), 256, 0, stream>>>(pts, perm, vv);
    knn_thr_kernel<<<64, 256, 0, stream>>>(vv, thrbuf);
    knn_collect_kernel<<<dim3(NCOL, 32, 2), 256, 0, stream>>>(pts, perm, thrbuf, segcnt, segIdx);
    knn_exact_kernel<<<64, 256, 0, stream>>>(pts, perm, segcnt, segIdx, knn);
    stats_kernel<<<dim3(256, 2), 256, 0, stream>>>(x, knn, w_pe, w_conv, wavept);
    finalize_kernel<<<1, 256, 0, stream>>>(wavept, g_pe, b_pe, g_conv, b_conv, scsh);
    fused_main_kernel<<<1024, 256, 0, stream>>>(x, knn, w_pe, w_conv, w_att1, w_att2,
                                                w_b1, w_b2, scsh, out);
}

// Round 13
// 381.032 us; speedup vs baseline: 1.0457x; 1.0372x over previous
//
#include <hip/hip_runtime.h>
#include <stdint.h>

#define PN 8192
#define SN 8192
#define KNB 16
#define SUBS 4                 // threshold subsample stride -> 2048 candidates
#define NCH1 8
#define CHUNK1 256             // subsample candidates per chunk
#define NCOL 8
#define COLCH (PN / NCOL)      // 1024 candidates per collect chunk
#define SEGCAP 32              // per-(sample,chunk) survivors: lambda=8, P(>32)~2e-12
#define MARGIN 1.0e-3f
#define NRCH 8
#define RCH (PN / NRCH)        // 1024

#define KEY_SENTINEL ((long long)0x8000000000000000ULL)
#define PD_SCALE 2199023255552.0   // 2^41: dd<1024 -> |scaled|<2^51; <<13 fits i64

// ---------------- helpers: branch-free sorted-16 maintenance ----------------
__device__ __forceinline__ void bitonic_sort16(float* b) {
#pragma unroll
    for (int k = 2; k <= 16; k <<= 1) {
#pragma unroll
        for (int j = k >> 1; j > 0; j >>= 1) {
#pragma unroll
            for (int i = 0; i < 16; ++i) {
                int l = i ^ j;
                if (l > i) {
                    float lo = fminf(b[i], b[l]), hi = fmaxf(b[i], b[l]);
                    bool up = ((i & k) == 0);
                    b[i] = up ? lo : hi;
                    b[l] = up ? hi : lo;
                }
            }
        }
    }
}
// r, b ascending sorted-16 -> r = lowest 16 of union, ascending.
__device__ __forceinline__ void merge16(float* r, const float* b) {
    float t[16];
#pragma unroll
    for (int i = 0; i < 16; ++i) t[i] = fminf(r[i], b[15 - i]);   // bitonic
#pragma unroll
    for (int j = 8; j > 0; j >>= 1) {
#pragma unroll
        for (int i = 0; i < 16; ++i) {
            int l = i ^ j;
            if (l > i) {
                float lo = fminf(t[i], t[l]), hi = fmaxf(t[i], t[l]);
                t[i] = lo; t[l] = hi;
            }
        }
    }
#pragma unroll
    for (int i = 0; i < 16; ++i) r[i] = t[i];
}

// ---------------- kernel 0: pack points (x,y,z,0) ----------------
__global__ void pack_pts_kernel(const float* __restrict__ x, float4* __restrict__ pts) {
    int i = blockIdx.x * 256 + threadIdx.x;           // 0 .. 2*PN-1
    int b = i >> 13, p = i & (PN - 1);
    const float* xb = x + (size_t)b * 4 * PN;
    pts[i] = make_float4(xb[p], xb[PN + p], xb[2 * PN + p], 0.f);
}

// ---------------- argsort stage A: partial rank counts (rank-by-counting) ----------------
__global__ __launch_bounds__(256) void rank_count_kernel(const float* __restrict__ rnd,
        unsigned short* __restrict__ rcnt) {
    __shared__ unsigned long long lk[RCH];            // 8 KB
    const int chunk = blockIdx.x, sg = blockIdx.y, b = blockIdx.z;
    const unsigned int* rb = (const unsigned int*)rnd + b * PN;   // [0,1) floats: bits order-preserving
    const int cbase = chunk * RCH;
    for (int c = threadIdx.x; c < RCH; c += 256) {
        int j = cbase + c;
        lk[c] = ((unsigned long long)rb[j] << 13) | (unsigned)j;
    }
    __syncthreads();
    const int i = sg * 256 + threadIdx.x;
    const unsigned long long ki = ((unsigned long long)rb[i] << 13) | (unsigned)i;
    int cnt = 0;
#pragma unroll 8
    for (int c = 0; c < RCH; ++c) cnt += (lk[c] < ki) ? 1 : 0;
    rcnt[(((size_t)(b * NRCH + chunk)) << 13) + i] = (unsigned short)cnt;
}

// ---------------- argsort stage B: sum partials, scatter perm[rank] = i ----------------
__global__ void rank_scatter_kernel(const unsigned short* __restrict__ rcnt,
                                    int* __restrict__ perm) {
    int t = blockIdx.x * 256 + threadIdx.x;           // 0 .. 2*PN-1
    int b = t >> 13, i = t & (PN - 1);
    int rank = 0;
#pragma unroll
    for (int ch = 0; ch < NRCH; ++ch)
        rank += rcnt[(((size_t)(b * NRCH + ch)) << 13) + i];
    perm[b * PN + rank] = i;
}

// ---------------- K1: per-(sample, subsample-chunk) sorted f32 top-16 distances ----------------
// Candidate stream is wave-uniform -> read straight from global (scalar-load path).
// Stride-4 SUBSAMPLE: subset's 16th order stat >= true d16.
__global__ __launch_bounds__(256) void knn_val16_kernel(const float4* __restrict__ pts,
        const int* __restrict__ perm, float* __restrict__ vv) {
    const int chunk = blockIdx.x, sg = blockIdx.y, b = blockIdx.z;
    const float4* pb = pts + b * PN;
    const int pbase = chunk * CHUNK1;
    const int s = sg * 256 + threadIdx.x;
    const float4 qp = pb[perm[b * PN + s]];
    float r[16];
#pragma unroll
    for (int i = 0; i < 16; ++i) r[i] = 3.0e38f;
    for (int t = 0; t < CHUNK1; t += 16) {
        float bv[16];
#pragma unroll
        for (int u = 0; u < 16; ++u) {
            float4 pp = pb[SUBS * (pbase + t + u)];   // uniform addr -> s_load
            float dx = qp.x - pp.x, dy = qp.y - pp.y, dz = qp.z - pp.z;
            bv[u] = dx * dx + dy * dy + dz * dz;
        }
        bitonic_sort16(bv);
        merge16(r, bv);
    }
    float* ov = vv + ((size_t)(b * NCH1 + chunk) * 16) * SN + s;
#pragma unroll
    for (int i = 0; i < 16; ++i) ov[(size_t)i * SN] = r[i];
}

// ---------------- K1.5: merge 8 sorted chunk value-lists -> subsample d16 -> thr ----------------
__global__ void knn_thr_kernel(const float* __restrict__ vv, float* __restrict__ thrbuf) {
    int t = blockIdx.x * 256 + threadIdx.x;           // 0 .. 2*SN-1
    int b = t >> 13, s = t & (SN - 1);
    float r[16], bl[16];
    const float* v0 = vv + ((size_t)(b * NCH1) * 16) * SN + s;
#pragma unroll
    for (int i = 0; i < 16; ++i) r[i] = v0[(size_t)i * SN];
    for (int ch = 1; ch < NCH1; ++ch) {
        const float* vc = vv + ((size_t)(b * NCH1 + ch) * 16) * SN + s;
#pragma unroll
        for (int i = 0; i < 16; ++i) bl[i] = vc[(size_t)i * SN];
        merge16(r, bl);
    }
    thrbuf[b * SN + s] = r[15] + MARGIN;              // >= true global d16 (subset bound)
}

// ---------------- K2: collect survivors into PRIVATE per-(sample,chunk) segments ----------------
// Wave-uniform candidate reads straight from global (scalar path, zero LDS).
// Thread owns (sample, chunk): sole writer of its segment/count -> no atomics,
// no init, fully deterministic.
__global__ __launch_bounds__(256) void knn_collect_kernel(const float4* __restrict__ pts,
        const int* __restrict__ perm, const float* __restrict__ thrbuf,
        unsigned short* __restrict__ segcnt, unsigned short* __restrict__ segIdx) {
    const int chunk = blockIdx.x, sg = blockIdx.y, b = blockIdx.z;
    const float4* pb = pts + b * PN;
    const int pbase = chunk * COLCH;
    const int s = sg * 256 + threadIdx.x;
    const int bs = b * SN + s;
    const float4 qp = pb[perm[bs]];
    const float thr = thrbuf[bs];
    unsigned short* seg = segIdx + ((size_t)bs * NCOL + chunk) * SEGCAP;
    int cnt = 0;
#pragma unroll 4
    for (int c = 0; c < COLCH; ++c) {
        float4 pp = pb[pbase + c];                    // uniform addr -> s_load
        float dx = qp.x - pp.x, dy = qp.y - pp.y, dz = qp.z - pp.z;
        float dd = dx * dx;
        dd += dy * dy;
        dd += dz * dz;
        if (dd < thr) {
            if (cnt < SEGCAP) seg[cnt] = (unsigned short)(pbase + c);
            ++cnt;
        }
    }
    segcnt[(size_t)bs * NCOL + chunk] = (unsigned short)cnt;
}

// ---------------- K3: exact f64 top-16 over segment survivors -> knn[b][rank][s] ----------------
// Top-16 kept in 16 NAMED i64 registers (k0..k15) -- array form spilled to scratch
// (VGPR_Count=32 evidence). Insertion network: all 16 selects independent, no chain.
// 4-wide candidate batching (ushort4 index read + 4 independent float4 gathers) for MLP.
// Tail lanes clamp index to 0 (valid point) and force key to sentinel: no poison-NaN UB.
#define MAKEKEY(pp, c, out) do { \
    double dx_ = qx - (double)(pp).x; \
    double dy_ = qy - (double)(pp).y; \
    double dz_ = qz - (double)(pp).z; \
    double dd_ = dx_ * dx_ + dy_ * dy_ + dz_ * dz_; \
    long long sc_ = (long long)floor(-dd_ * PD_SCALE); \
    (out) = (sc_ << 13) | (long long)(8191 - (c)); \
} while (0)

#define INS16(kkv) do { long long nk = (kkv); if (nk > k15) { \
    k15 = (nk > k14) ? k14 : ((nk > k15) ? nk : k15); \
    k14 = (nk > k13) ? k13 : ((nk > k14) ? nk : k14); \
    k13 = (nk > k12) ? k12 : ((nk > k13) ? nk : k13); \
    k12 = (nk > k11) ? k11 : ((nk > k12) ? nk : k12); \
    k11 = (nk > k10) ? k10 : ((nk > k11) ? nk : k11); \
    k10 = (nk > k9 ) ? k9  : ((nk > k10) ? nk : k10); \
    k9  = (nk > k8 ) ? k8  : ((nk > k9 ) ? nk : k9 ); \
    k8  = (nk > k7 ) ? k7  : ((nk > k8 ) ? nk : k8 ); \
    k7  = (nk > k6 ) ? k6  : ((nk > k7 ) ? nk : k7 ); \
    k6  = (nk > k5 ) ? k5  : ((nk > k6 ) ? nk : k6 ); \
    k5  = (nk > k4 ) ? k4  : ((nk > k5 ) ? nk : k5 ); \
    k4  = (nk > k3 ) ? k3  : ((nk > k4 ) ? nk : k4 ); \
    k3  = (nk > k2 ) ? k2  : ((nk > k3 ) ? nk : k3 ); \
    k2  = (nk > k1 ) ? k1  : ((nk > k2 ) ? nk : k2 ); \
    k1  = (nk > k0 ) ? k0  : ((nk > k1 ) ? nk : k1 ); \
    k0  = (nk > k0 ) ? nk  : k0; \
} } while (0)

__global__ __launch_bounds__(256) void knn_exact_kernel(const float4* __restrict__ pts,
        const int* __restrict__ perm, const unsigned short* __restrict__ segcnt,
        const unsigned short* __restrict__ segIdx, int* __restrict__ knn) {
    int t = blockIdx.x * 256 + threadIdx.x;           // 0 .. 2*SN-1
    int b = t >> 13, s = t & (SN - 1);
    const int bs = b * SN + s;
    const float4* pb = pts + b * PN;
    const float4 qp = pb[perm[bs]];
    const double qx = qp.x, qy = qp.y, qz = qp.z;
    long long k0 = KEY_SENTINEL, k1 = KEY_SENTINEL, k2 = KEY_SENTINEL, k3 = KEY_SENTINEL,
              k4 = KEY_SENTINEL, k5 = KEY_SENTINEL, k6 = KEY_SENTINEL, k7 = KEY_SENTINEL,
              k8 = KEY_SENTINEL, k9 = KEY_SENTINEL, k10 = KEY_SENTINEL, k11 = KEY_SENTINEL,
              k12 = KEY_SENTINEL, k13 = KEY_SENTINEL, k14 = KEY_SENTINEL, k15 = KEY_SENTINEL;
    const unsigned short* scp = segcnt + (size_t)bs * NCOL;
    ushort4 c03 = *reinterpret_cast<const ushort4*>(scp);
    ushort4 c47 = *reinterpret_cast<const ushort4*>(scp + 4);
    int ns[NCOL] = {c03.x, c03.y, c03.z, c03.w, c47.x, c47.y, c47.z, c47.w};
    bool ovf = false;
#pragma unroll
    for (int ch = 0; ch < NCOL; ++ch) ovf |= (ns[ch] > SEGCAP);
    if (!ovf) {
        const unsigned short* base = segIdx + (size_t)bs * (NCOL * SEGCAP);
#pragma unroll
        for (int ch = 0; ch < NCOL; ++ch) {
            const unsigned short* seg = base + ch * SEGCAP;
            const int n = ns[ch];
            for (int u = 0; u < n; u += 4) {
                ushort4 i4 = *reinterpret_cast<const ushort4*>(seg + u);  // 8B-aligned
                int c0i = (int)i4.x;
                int c1i = (u + 1 < n) ? (int)i4.y : 0;
                int c2i = (u + 2 < n) ? (int)i4.z : 0;
                int c3i = (u + 3 < n) ? (int)i4.w : 0;
                float4 p0 = pb[c0i], p1 = pb[c1i], p2 = pb[c2i], p3 = pb[c3i];
                long long kk0, kk1, kk2, kk3;
                MAKEKEY(p0, c0i, kk0);
                MAKEKEY(p1, c1i, kk1);
                MAKEKEY(p2, c2i, kk2);
                MAKEKEY(p3, c3i, kk3);
                kk1 = (u + 1 < n) ? kk1 : KEY_SENTINEL;
                kk2 = (u + 2 < n) ? kk2 : KEY_SENTINEL;
                kk3 = (u + 3 < n) ? kk3 : KEY_SENTINEL;
                INS16(kk0);
                INS16(kk1);
                INS16(kk2);
                INS16(kk3);
            }
        }
    } else {
        // deterministic exact fallback (P ~ 2e-12): full scan
        for (int c = 0; c < PN; ++c) {
            float4 pp = pb[c];
            long long kk;
            MAKEKEY(pp, c, kk);
            INS16(kk);
        }
    }
    int* ob = knn + (size_t)b * (SN * KNB);
    ob[(size_t)0 * SN + s]  = 8191 - (int)(k0 & 8191);
    ob[(size_t)1 * SN + s]  = 8191 - (int)(k1 & 8191);
    ob[(size_t)2 * SN + s]  = 8191 - (int)(k2 & 8191);
    ob[(size_t)3 * SN + s]  = 8191 - (int)(k3 & 8191);
    ob[(size_t)4 * SN + s]  = 8191 - (int)(k4 & 8191);
    ob[(size_t)5 * SN + s]  = 8191 - (int)(k5 & 8191);
    ob[(size_t)6 * SN + s]  = 8191 - (int)(k6 & 8191);
    ob[(size_t)7 * SN + s]  = 8191 - (int)(k7 & 8191);
    ob[(size_t)8 * SN + s]  = 8191 - (int)(k8 & 8191);
    ob[(size_t)9 * SN + s]  = 8191 - (int)(k9 & 8191);
    ob[(size_t)10 * SN + s] = 8191 - (int)(k10 & 8191);
    ob[(size_t)11 * SN + s] = 8191 - (int)(k11 & 8191);
    ob[(size_t)12 * SN + s] = 8191 - (int)(k12 & 8191);
    ob[(size_t)13 * SN + s] = 8191 - (int)(k13 & 8191);
    ob[(size_t)14 * SN + s] = 8191 - (int)(k14 & 8191);
    ob[(size_t)15 * SN + s] = 8191 - (int)(k15 & 8191);
}

// ---------------- kernel 4: GroupNorm statistics ----------------
__global__ __launch_bounds__(256) void stats_kernel(const float* __restrict__ x,
        const int* __restrict__ knn, const float* __restrict__ w_pe,
        const float* __restrict__ w_conv, float* __restrict__ wavepart) {
    const int blk = blockIdx.x;                       // 0..255
    const int b = blockIdx.y;
    const int w = threadIdx.x >> 6, l = threadIdx.x & 63;
    float wr[10];
#pragma unroll
    for (int c = 0; c < 10; ++c) wr[c] = 0.f;
    if (l < 32) {
#pragma unroll
        for (int c = 0; c < 4; ++c) wr[c] = w_conv[l * 4 + c];
    } else {
#pragma unroll
        for (int c = 0; c < 10; ++c) wr[c] = w_pe[(l - 32) * 10 + c];
    }
    const float* xb = x + (size_t)b * 4 * PN;
    const int* kb = knn + (size_t)b * (SN * KNB);
    float s1 = 0.f, s2 = 0.f;
    const int nbase = blk * 512 + w * 128;
#pragma unroll 2
    for (int it = 0; it < 128; ++it) {
        int n = nbase + it;
        int i  = kb[n];
        int i0 = kb[n & ~15];
        float xa0 = xb[i], xa1 = xb[PN + i], xa2 = xb[2 * PN + i], xa3 = xb[3 * PN + i];
        float xc0 = xb[i0], xc1 = xb[PN + i0], xc2 = xb[2 * PN + i0];
        float d0 = xa0 - xc0, d1 = xa1 - xc1, d2 = xa2 - xc2;
        float dd = d0 * d0; dd += d1 * d1; dd += d2 * d2;
        float temp = sqrtf(fmaxf(dd, 1e-12f));
        float r;
        if (l < 32) {
            r = wr[0] * xa0 + wr[1] * xa1 + wr[2] * xa2 + wr[3] * xa3;
        } else {
            r = wr[0] * xa0 + wr[1] * xa1 + wr[2] * xa2
              + wr[3] * xc0 + wr[4] * xc1 + wr[5] * xc2
              + wr[6] * d0 + wr[7] * d1 + wr[8] * d2 + wr[9] * temp;
        }
        s1 += r;
        s2 += r * r;
    }
    const int wslot = blk * 4 + w;                    // 0..1023
    wavepart[((size_t)b * 1024 + wslot) * 128 + l] = s1;
    wavepart[((size_t)b * 1024 + wslot) * 128 + 64 + l] = s2;
}

// ---------------- kernel 5: finalize stats -> per-channel scale/shift ----------------
__global__ void finalize_kernel(const float* __restrict__ wavepart,
        const float* __restrict__ g_pe, const float* __restrict__ b_pe,
        const float* __restrict__ g_conv, const float* __restrict__ b_conv,
        float* __restrict__ scsh) {
    const int t = threadIdx.x;                        // 0..255
    const int b = t >> 7, k = t & 127;
    float acc = 0.f;
    for (int w = 0; w < 1024; ++w) acc += wavepart[((size_t)b * 1024 + w) * 128 + k];
    __shared__ float sums[2][128];
    sums[b][k] = acc;
    __syncthreads();
    if (k < 64) {
        const float N = 131072.f;
        float mean = sums[b][k] / N;
        float var = sums[b][64 + k] / N - mean * mean;
        float rstd = 1.0f / sqrtf(var + 1e-5f);
        float gam = (k < 32) ? g_conv[k] : g_pe[k - 32];
        float bet = (k < 32) ? b_conv[k] : b_pe[k - 32];
        float sc = gam * rstd;
        scsh[(b * 64 + k) * 2 + 0] = sc;
        scsh[(b * 64 + k) * 2 + 1] = bet - mean * sc;
    }
}

// ---------------- kernel 6: fused feature/attention/output ----------------
__global__ __launch_bounds__(256) void fused_main_kernel(
        const float* __restrict__ x, const int* __restrict__ knn,
        const float* __restrict__ w_pe, const float* __restrict__ w_conv,
        const float* __restrict__ w_att1, const float* __restrict__ w_att2,
        const float* __restrict__ w_b1, const float* __restrict__ w_b2,
        const float* __restrict__ scsh, float* __restrict__ out) {
    __shared__ float wb1T[64 * 64];                   // [c][o]
    __shared__ float wb2T[4 * 64];                    // [c][o]
    for (int i = threadIdx.x; i < 64 * 64; i += 256) wb1T[(i & 63) * 64 + (i >> 6)] = w_b1[i];
    { int i = threadIdx.x; wb2T[(i & 3) * 64 + (i >> 2)] = w_b2[i]; }
    __syncthreads();
    const int gidx = blockIdx.x;                      // 0..1023
    const int b = gidx >> 9;
    const int sb = (gidx & 511) << 4;
    const int l = threadIdx.x & 63;
    const int w = threadIdx.x >> 6;
    const int g = l >> 4, j = l & 15;
    const int s = sb + (w << 2) + g;
    const int srcl = g << 4;
    const float* xb = x + (size_t)b * 4 * PN;
    const int i1 = knn[(size_t)b * (SN * KNB) + (size_t)s * KNB + j];
    float xa0 = xb[i1], xa1 = xb[PN + i1], xa2 = xb[2 * PN + i1], xa3 = xb[3 * PN + i1];
    float xc0 = __shfl(xa0, srcl), xc1 = __shfl(xa1, srcl);
    float xc2 = __shfl(xa2, srcl), xc3 = __shfl(xa3, srcl);
    float d0 = xa0 - xc0, d1 = xa1 - xc1, d2 = xa2 - xc2;
    float dd = d0 * d0; dd += d1 * d1; dd += d2 * d2;
    float temp = sqrtf(fmaxf(dd, 1e-12f));
    float pem[10] = {xa0, xa1, xa2, xc0, xc1, xc2, d0, d1, d2, temp};
    float f[64];
    const float* ssb = scsh + b * 128;
#pragma unroll
    for (int o = 0; o < 32; ++o) {
        float r = w_conv[o * 4 + 0] * xa0;
        r += w_conv[o * 4 + 1] * xa1;
        r += w_conv[o * 4 + 2] * xa2;
        r += w_conv[o * 4 + 3] * xa3;
        r = r * ssb[o * 2 + 0] + ssb[o * 2 + 1];
        f[o] = (r >= 0.f) ? r : 0.2f * r;
    }
#pragma unroll
    for (int o = 0; o < 32; ++o) {
        float r = 0.f;
#pragma unroll
        for (int c = 0; c < 10; ++c) r += w_pe[o * 10 + c] * pem[c];
        r = r * ssb[(32 + o) * 2 + 0] + ssb[(32 + o) * 2 + 1];
        f[32 + o] = (r >= 0.f) ? r : 0.2f * r;
    }
    float logit = 0.f;
#pragma unroll 2
    for (int o = 0; o < 32; ++o) {
        float a = 0.f;
#pragma unroll
        for (int c = 0; c < 64; ++c) a += w_att1[o * 64 + c] * f[c];
        a = (a >= 0.f) ? a : 0.2f * a;
        logit += w_att2[o] * a;
    }
    float mx = logit;
    mx = fmaxf(mx, __shfl_xor(mx, 1));
    mx = fmaxf(mx, __shfl_xor(mx, 2));
    mx = fmaxf(mx, __shfl_xor(mx, 4));
    mx = fmaxf(mx, __shfl_xor(mx, 8));
    float e = expf(logit - mx);
    float se = e;
    se += __shfl_xor(se, 1);
    se += __shfl_xor(se, 2);
    se += __shfl_xor(se, 4);
    se += __shfl_xor(se, 8);
    float att = e / se;
#pragma unroll
    for (int c = 0; c < 64; ++c) {
        float v = f[c] * att;
        v += __shfl_xor(v, 1);
        v += __shfl_xor(v, 2);
        v += __shfl_xor(v, 4);
        v += __shfl_xor(v, 8);
        f[c] = v;
    }
    float o0 = 0.f, o1 = 0.f, o2 = 0.f, o3 = 0.f;
#pragma unroll
    for (int c = 0; c < 64; ++c) {
        float4 wv = *reinterpret_cast<const float4*>(&wb1T[c * 64 + 4 * j]);
        o0 += wv.x * f[c]; o1 += wv.y * f[c]; o2 += wv.z * f[c]; o3 += wv.w * f[c];
    }
    {
        float4 wv = *reinterpret_cast<const float4*>(&wb2T[0 * 64 + 4 * j]);
        o0 += wv.x * xc0; o1 += wv.y * xc0; o2 += wv.z * xc0; o3 += wv.w * xc0;
        wv = *reinterpret_cast<const float4*>(&wb2T[1 * 64 + 4 * j]);
        o0 += wv.x * xc1; o1 += wv.y * xc1; o2 += wv.z * xc1; o3 += wv.w * xc1;
        wv = *reinterpret_cast<const float4*>(&wb2T[2 * 64 + 4 * j]);
        o0 += wv.x * xc2; o1 += wv.y * xc2; o2 += wv.z * xc2; o3 += wv.w * xc2;
        wv = *reinterpret_cast<const float4*>(&wb2T[3 * 64 + 4 * j]);
        o0 += wv.x * xc3; o1 += wv.y * xc3; o2 += wv.z * xc3; o3 += wv.w * xc3;
    }
    o0 = (o0 >= 0.f) ? o0 : 0.1f * o0;
    o1 = (o1 >= 0.f) ? o1 : 0.1f * o1;
    o2 = (o2 >= 0.f) ? o2 : 0.1f * o2;
    o3 = (o3 >= 0.f) ? o3 : 0.1f * o3;
    float* ob = out + (size_t)b * 67 * SN;
    const int oc = 3 + 4 * j;
    ob[(size_t)(oc + 0) * SN + s] = o0;
    ob[(size_t)(oc + 1) * SN + s] = o1;
    ob[(size_t)(oc + 2) * SN + s] = o2;
    ob[(size_t)(oc + 3) * SN + s] = o3;
    if (j < 3) ob[(size_t)j * SN + s] = (j == 0) ? xc0 : ((j == 1) ? xc1 : xc2);
}

extern "C" void kernel_launch(void* const* d_in, const int* in_sizes, int n_in,
                              void* d_out, int out_size, void* d_ws, size_t ws_size,
                              hipStream_t stream) {
    (void)in_sizes; (void)n_in; (void)out_size; (void)ws_size;
    const float* x      = (const float*)d_in[0];
    const float* rnd    = (const float*)d_in[1];
    const float* w_pe   = (const float*)d_in[2];
    const float* g_pe   = (const float*)d_in[3];
    const float* b_pe   = (const float*)d_in[4];
    const float* w_conv = (const float*)d_in[5];
    const float* g_conv = (const float*)d_in[6];
    const float* b_conv = (const float*)d_in[7];
    const float* w_att1 = (const float*)d_in[8];
    const float* w_att2 = (const float*)d_in[9];
    const float* w_b1   = (const float*)d_in[10];
    const float* w_b2   = (const float*)d_in[11];
    float* out = (float*)d_out;
    char* ws = (char*)d_ws;
    // workspace carve-up (bytes), peak ~10.09 MB (< proven 10.81 MB).
    // Region A [327680, 8716288) = 8 MB, time-shared sequentially:
    //   rcnt (256K; rank_count->scatter) -> vv (8MB; K1->K1.5)
    //   -> segIdx (8MB exactly; collect->exact) -> wavept (1MB; stats->finalize)
    float4*         pts    = (float4*)        (ws + 0);          //   262,144
    int*            perm   = (int*)           (ws + 262144);     //    65,536
    unsigned short* rcnt   = (unsigned short*)(ws + 327680);     //   262,144 (A)
    float*          vv     = (float*)         (ws + 327680);     // 8,388,608 (A)
    unsigned short* segIdx = (unsigned short*)(ws + 327680);     // 8,388,608 (A) 16384*8*32*2
    float*          wavept = (float*)         (ws + 327680);     // 1,048,576 (A)
    float*          thrbuf = (float*)         (ws + 8716288);    //    65,536
    unsigned short* segcnt = (unsigned short*)(ws + 8781824);    //   262,144
    int*            knn    = (int*)           (ws + 9043968);    // 1,048,576
    float*          scsh   = (float*)         (ws + 10092544);   //     1,024

    pack_pts_kernel<<<64, 256, 0, stream>>>(x, pts);
    rank_count_kernel<<<dim3(NRCH, 32, 2), 256, 0, stream>>>(rnd, rcnt);
    rank_scatter_kernel<<<64, 256, 0, stream>>>(rcnt, perm);
    knn_val16_kernel<<<dim3(NCH1, 32, 2), 256, 0, stream>>>(pts, perm, vv);
    knn_thr_kernel<<<64, 256, 0, stream>>>(vv, thrbuf);
    knn_collect_kernel<<<dim3(NCOL, 32, 2), 256, 0, stream>>>(pts, perm, thrbuf, segcnt, segIdx);
    knn_exact_kernel<<<64, 256, 0, stream>>>(pts, perm, segcnt, segIdx, knn);
    stats_kernel<<<dim3(256, 2), 256, 0, stream>>>(x, knn, w_pe, w_conv, wavept);
    finalize_kernel<<<1, 256, 0, stream>>>(wavept, g_pe, b_pe, g_conv, b_conv, scsh);
    fused_main_kernel<<<1024, 256, 0, stream>>>(x, knn, w_pe, w_conv, w_att1, w_att2,
                                                w_b1, w_b2, scsh, out);
}

// Round 14
// 354.766 us; speedup vs baseline: 1.1231x; 1.0740x over previous
//
#include <hip/hip_runtime.h>
#include <stdint.h>

#define PN 8192
#define SN 8192
#define KNB 16
#define SUBS 4                 // threshold subsample stride -> 2048 candidates
#define NCH1 8
#define CHUNK1 256             // subsample candidates per chunk
#define NCOL 8
#define COLCH (PN / NCOL)      // 1024 candidates per collect chunk
#define SEGCAP 32              // per-(sample,chunk) survivors: lambda=8, P(>32)~2e-12
#define MARGIN 1.0e-3f
#define NRCH 8
#define RCH (PN / NRCH)        // 1024

#define KEY_SENTINEL ((long long)0x8000000000000000ULL)
#define PD_SCALE 2199023255552.0   // 2^41: dd<1024 -> |scaled|<2^51; <<13 fits i64

// ---------------- helpers: branch-free sorted-16 maintenance ----------------
__device__ __forceinline__ void bitonic_sort16(float* b) {
#pragma unroll
    for (int k = 2; k <= 16; k <<= 1) {
#pragma unroll
        for (int j = k >> 1; j > 0; j >>= 1) {
#pragma unroll
            for (int i = 0; i < 16; ++i) {
                int l = i ^ j;
                if (l > i) {
                    float lo = fminf(b[i], b[l]), hi = fmaxf(b[i], b[l]);
                    bool up = ((i & k) == 0);
                    b[i] = up ? lo : hi;
                    b[l] = up ? hi : lo;
                }
            }
        }
    }
}
// r, b ascending sorted-16 -> r = lowest 16 of union, ascending.
__device__ __forceinline__ void merge16(float* r, const float* b) {
    float t[16];
#pragma unroll
    for (int i = 0; i < 16; ++i) t[i] = fminf(r[i], b[15 - i]);   // bitonic
#pragma unroll
    for (int j = 8; j > 0; j >>= 1) {
#pragma unroll
        for (int i = 0; i < 16; ++i) {
            int l = i ^ j;
            if (l > i) {
                float lo = fminf(t[i], t[l]), hi = fmaxf(t[i], t[l]);
                t[i] = lo; t[l] = hi;
            }
        }
    }
#pragma unroll
    for (int i = 0; i < 16; ++i) r[i] = t[i];
}

// ---------------- kernel 0: pack points (x,y,z,0) ----------------
__global__ void pack_pts_kernel(const float* __restrict__ x, float4* __restrict__ pts) {
    int i = blockIdx.x * 256 + threadIdx.x;           // 0 .. 2*PN-1
    int b = i >> 13, p = i & (PN - 1);
    const float* xb = x + (size_t)b * 4 * PN;
    pts[i] = make_float4(xb[p], xb[PN + p], xb[2 * PN + p], 0.f);
}

// ---------------- argsort stage A: partial rank counts (rank-by-counting) ----------------
__global__ __launch_bounds__(256) void rank_count_kernel(const float* __restrict__ rnd,
        unsigned short* __restrict__ rcnt) {
    __shared__ unsigned long long lk[RCH];            // 8 KB
    const int chunk = blockIdx.x, sg = blockIdx.y, b = blockIdx.z;
    const unsigned int* rb = (const unsigned int*)rnd + b * PN;   // [0,1) floats: bits order-preserving
    const int cbase = chunk * RCH;
    for (int c = threadIdx.x; c < RCH; c += 256) {
        int j = cbase + c;
        lk[c] = ((unsigned long long)rb[j] << 13) | (unsigned)j;
    }
    __syncthreads();
    const int i = sg * 256 + threadIdx.x;
    const unsigned long long ki = ((unsigned long long)rb[i] << 13) | (unsigned)i;
    int cnt = 0;
#pragma unroll 8
    for (int c = 0; c < RCH; ++c) cnt += (lk[c] < ki) ? 1 : 0;
    rcnt[(((size_t)(b * NRCH + chunk)) << 13) + i] = (unsigned short)cnt;
}

// ---------------- argsort stage B: sum partials, scatter perm[rank] = i ----------------
__global__ void rank_scatter_kernel(const unsigned short* __restrict__ rcnt,
                                    int* __restrict__ perm) {
    int t = blockIdx.x * 256 + threadIdx.x;           // 0 .. 2*PN-1
    int b = t >> 13, i = t & (PN - 1);
    int rank = 0;
#pragma unroll
    for (int ch = 0; ch < NRCH; ++ch)
        rank += rcnt[(((size_t)(b * NRCH + ch)) << 13) + i];
    perm[b * PN + rank] = i;
}

// ---------------- K1: per-(sample, subsample-chunk) sorted f32 top-16 distances ----------------
// Candidate stream is wave-uniform -> read straight from global (scalar-load path).
// Stride-4 SUBSAMPLE: subset's 16th order stat >= true d16.
__global__ __launch_bounds__(256) void knn_val16_kernel(const float4* __restrict__ pts,
        const int* __restrict__ perm, float* __restrict__ vv) {
    const int chunk = blockIdx.x, sg = blockIdx.y, b = blockIdx.z;
    const float4* pb = pts + b * PN;
    const int pbase = chunk * CHUNK1;
    const int s = sg * 256 + threadIdx.x;
    const float4 qp = pb[perm[b * PN + s]];
    float r[16];
#pragma unroll
    for (int i = 0; i < 16; ++i) r[i] = 3.0e38f;
    for (int t = 0; t < CHUNK1; t += 16) {
        float bv[16];
#pragma unroll
        for (int u = 0; u < 16; ++u) {
            float4 pp = pb[SUBS * (pbase + t + u)];   // uniform addr -> s_load
            float dx = qp.x - pp.x, dy = qp.y - pp.y, dz = qp.z - pp.z;
            bv[u] = dx * dx + dy * dy + dz * dz;
        }
        bitonic_sort16(bv);
        merge16(r, bv);
    }
    float* ov = vv + ((size_t)(b * NCH1 + chunk) * 16) * SN + s;
#pragma unroll
    for (int i = 0; i < 16; ++i) ov[(size_t)i * SN] = r[i];
}

// ---------------- K1.5: merge 8 sorted chunk value-lists -> subsample d16 -> thr ----------------
__global__ void knn_thr_kernel(const float* __restrict__ vv, float* __restrict__ thrbuf) {
    int t = blockIdx.x * 256 + threadIdx.x;           // 0 .. 2*SN-1
    int b = t >> 13, s = t & (SN - 1);
    float r[16], bl[16];
    const float* v0 = vv + ((size_t)(b * NCH1) * 16) * SN + s;
#pragma unroll
    for (int i = 0; i < 16; ++i) r[i] = v0[(size_t)i * SN];
    for (int ch = 1; ch < NCH1; ++ch) {
        const float* vc = vv + ((size_t)(b * NCH1 + ch) * 16) * SN + s;
#pragma unroll
        for (int i = 0; i < 16; ++i) bl[i] = vc[(size_t)i * SN];
        merge16(r, bl);
    }
    thrbuf[b * SN + s] = r[15] + MARGIN;              // >= true global d16 (subset bound)
}

// ---------------- K2: collect survivors into PRIVATE per-(sample,chunk) segments ----------------
// 8-wide software pipeline: prefetch the next 8 candidates into NAMED float4 regs
// while processing the current 8 -> >=8 loads in flight (round-13 evidence: VGPR=8,
// SGPR=32 => single s_load in flight, ~200cy exposed latency per candidate).
// Thread owns (sample, chunk): sole writer of its segment/count -> no atomics,
// no init, fully deterministic.
#define COLPROC(pp, cidx) do { \
    float dx_ = qp.x - (pp).x, dy_ = qp.y - (pp).y, dz_ = qp.z - (pp).z; \
    float dd_ = dx_ * dx_; dd_ += dy_ * dy_; dd_ += dz_ * dz_; \
    if (dd_ < thr) { if (cnt < SEGCAP) seg[cnt] = (unsigned short)(cidx); ++cnt; } \
} while (0)

__global__ __launch_bounds__(256) void knn_collect_kernel(const float4* __restrict__ pts,
        const int* __restrict__ perm, const float* __restrict__ thrbuf,
        unsigned short* __restrict__ segcnt, unsigned short* __restrict__ segIdx) {
    const int chunk = blockIdx.x, sg = blockIdx.y, b = blockIdx.z;
    const float4* pb = pts + b * PN;
    const int pbase = chunk * COLCH;
    const int s = sg * 256 + threadIdx.x;
    const int bs = b * SN + s;
    const float4 qp = pb[perm[bs]];
    const float thr = thrbuf[bs];
    unsigned short* seg = segIdx + ((size_t)bs * NCOL + chunk) * SEGCAP;
    int cnt = 0;
    const float4* cp = pb + pbase;
    float4 a0 = cp[0], a1 = cp[1], a2 = cp[2], a3 = cp[3];
    float4 a4 = cp[4], a5 = cp[5], a6 = cp[6], a7 = cp[7];
    int c = 0;
    for (; c < COLCH - 8; c += 8) {
        float4 n0 = cp[c + 8],  n1 = cp[c + 9],  n2 = cp[c + 10], n3 = cp[c + 11];
        float4 n4 = cp[c + 12], n5 = cp[c + 13], n6 = cp[c + 14], n7 = cp[c + 15];
        COLPROC(a0, pbase + c + 0);
        COLPROC(a1, pbase + c + 1);
        COLPROC(a2, pbase + c + 2);
        COLPROC(a3, pbase + c + 3);
        COLPROC(a4, pbase + c + 4);
        COLPROC(a5, pbase + c + 5);
        COLPROC(a6, pbase + c + 6);
        COLPROC(a7, pbase + c + 7);
        a0 = n0; a1 = n1; a2 = n2; a3 = n3;
        a4 = n4; a5 = n5; a6 = n6; a7 = n7;
    }
    COLPROC(a0, pbase + c + 0);
    COLPROC(a1, pbase + c + 1);
    COLPROC(a2, pbase + c + 2);
    COLPROC(a3, pbase + c + 3);
    COLPROC(a4, pbase + c + 4);
    COLPROC(a5, pbase + c + 5);
    COLPROC(a6, pbase + c + 6);
    COLPROC(a7, pbase + c + 7);
    segcnt[(size_t)bs * NCOL + chunk] = (unsigned short)cnt;
}

// ---------------- K3: exact f64 top-16 over segment survivors -> knn[b][rank][s] ----------------
// Top-16 kept in 16 NAMED i64 registers (k0..k15); insertion network with independent
// selects; 4-wide candidate batching for MLP. Tail lanes clamp index to 0 and force
// key to sentinel: no poison-NaN UB.
#define MAKEKEY(pp, c, out) do { \
    double dx_ = qx - (double)(pp).x; \
    double dy_ = qy - (double)(pp).y; \
    double dz_ = qz - (double)(pp).z; \
    double dd_ = dx_ * dx_ + dy_ * dy_ + dz_ * dz_; \
    long long sc_ = (long long)floor(-dd_ * PD_SCALE); \
    (out) = (sc_ << 13) | (long long)(8191 - (c)); \
} while (0)

#define INS16(kkv) do { long long nk = (kkv); if (nk > k15) { \
    k15 = (nk > k14) ? k14 : ((nk > k15) ? nk : k15); \
    k14 = (nk > k13) ? k13 : ((nk > k14) ? nk : k14); \
    k13 = (nk > k12) ? k12 : ((nk > k13) ? nk : k13); \
    k12 = (nk > k11) ? k11 : ((nk > k12) ? nk : k12); \
    k11 = (nk > k10) ? k10 : ((nk > k11) ? nk : k11); \
    k10 = (nk > k9 ) ? k9  : ((nk > k10) ? nk : k10); \
    k9  = (nk > k8 ) ? k8  : ((nk > k9 ) ? nk : k9 ); \
    k8  = (nk > k7 ) ? k7  : ((nk > k8 ) ? nk : k8 ); \
    k7  = (nk > k6 ) ? k6  : ((nk > k7 ) ? nk : k7 ); \
    k6  = (nk > k5 ) ? k5  : ((nk > k6 ) ? nk : k6 ); \
    k5  = (nk > k4 ) ? k4  : ((nk > k5 ) ? nk : k5 ); \
    k4  = (nk > k3 ) ? k3  : ((nk > k4 ) ? nk : k4 ); \
    k3  = (nk > k2 ) ? k2  : ((nk > k3 ) ? nk : k3 ); \
    k2  = (nk > k1 ) ? k1  : ((nk > k2 ) ? nk : k2 ); \
    k1  = (nk > k0 ) ? k0  : ((nk > k1 ) ? nk : k1 ); \
    k0  = (nk > k0 ) ? nk  : k0; \
} } while (0)

__global__ __launch_bounds__(256) void knn_exact_kernel(const float4* __restrict__ pts,
        const int* __restrict__ perm, const unsigned short* __restrict__ segcnt,
        const unsigned short* __restrict__ segIdx, int* __restrict__ knn) {
    int t = blockIdx.x * 256 + threadIdx.x;           // 0 .. 2*SN-1
    int b = t >> 13, s = t & (SN - 1);
    const int bs = b * SN + s;
    const float4* pb = pts + b * PN;
    const float4 qp = pb[perm[bs]];
    const double qx = qp.x, qy = qp.y, qz = qp.z;
    long long k0 = KEY_SENTINEL, k1 = KEY_SENTINEL, k2 = KEY_SENTINEL, k3 = KEY_SENTINEL,
              k4 = KEY_SENTINEL, k5 = KEY_SENTINEL, k6 = KEY_SENTINEL, k7 = KEY_SENTINEL,
              k8 = KEY_SENTINEL, k9 = KEY_SENTINEL, k10 = KEY_SENTINEL, k11 = KEY_SENTINEL,
              k12 = KEY_SENTINEL, k13 = KEY_SENTINEL, k14 = KEY_SENTINEL, k15 = KEY_SENTINEL;
    const unsigned short* scp = segcnt + (size_t)bs * NCOL;
    ushort4 c03 = *reinterpret_cast<const ushort4*>(scp);
    ushort4 c47 = *reinterpret_cast<const ushort4*>(scp + 4);
    int ns[NCOL] = {c03.x, c03.y, c03.z, c03.w, c47.x, c47.y, c47.z, c47.w};
    bool ovf = false;
#pragma unroll
    for (int ch = 0; ch < NCOL; ++ch) ovf |= (ns[ch] > SEGCAP);
    if (!ovf) {
        const unsigned short* base = segIdx + (size_t)bs * (NCOL * SEGCAP);
#pragma unroll
        for (int ch = 0; ch < NCOL; ++ch) {
            const unsigned short* seg = base + ch * SEGCAP;
            const int n = ns[ch];
            for (int u = 0; u < n; u += 4) {
                ushort4 i4 = *reinterpret_cast<const ushort4*>(seg + u);  // 8B-aligned
                int c0i = (int)i4.x;
                int c1i = (u + 1 < n) ? (int)i4.y : 0;
                int c2i = (u + 2 < n) ? (int)i4.z : 0;
                int c3i = (u + 3 < n) ? (int)i4.w : 0;
                float4 p0 = pb[c0i], p1 = pb[c1i], p2 = pb[c2i], p3 = pb[c3i];
                long long kk0, kk1, kk2, kk3;
                MAKEKEY(p0, c0i, kk0);
                MAKEKEY(p1, c1i, kk1);
                MAKEKEY(p2, c2i, kk2);
                MAKEKEY(p3, c3i, kk3);
                kk1 = (u + 1 < n) ? kk1 : KEY_SENTINEL;
                kk2 = (u + 2 < n) ? kk2 : KEY_SENTINEL;
                kk3 = (u + 3 < n) ? kk3 : KEY_SENTINEL;
                INS16(kk0);
                INS16(kk1);
                INS16(kk2);
                INS16(kk3);
            }
        }
    } else {
        // deterministic exact fallback (P ~ 2e-12): full scan
        for (int c = 0; c < PN; ++c) {
            float4 pp = pb[c];
            long long kk;
            MAKEKEY(pp, c, kk);
            INS16(kk);
        }
    }
    int* ob = knn + (size_t)b * (SN * KNB);
    ob[(size_t)0 * SN + s]  = 8191 - (int)(k0 & 8191);
    ob[(size_t)1 * SN + s]  = 8191 - (int)(k1 & 8191);
    ob[(size_t)2 * SN + s]  = 8191 - (int)(k2 & 8191);
    ob[(size_t)3 * SN + s]  = 8191 - (int)(k3 & 8191);
    ob[(size_t)4 * SN + s]  = 8191 - (int)(k4 & 8191);
    ob[(size_t)5 * SN + s]  = 8191 - (int)(k5 & 8191);
    ob[(size_t)6 * SN + s]  = 8191 - (int)(k6 & 8191);
    ob[(size_t)7 * SN + s]  = 8191 - (int)(k7 & 8191);
    ob[(size_t)8 * SN + s]  = 8191 - (int)(k8 & 8191);
    ob[(size_t)9 * SN + s]  = 8191 - (int)(k9 & 8191);
    ob[(size_t)10 * SN + s] = 8191 - (int)(k10 & 8191);
    ob[(size_t)11 * SN + s] = 8191 - (int)(k11 & 8191);
    ob[(size_t)12 * SN + s] = 8191 - (int)(k12 & 8191);
    ob[(size_t)13 * SN + s] = 8191 - (int)(k13 & 8191);
    ob[(size_t)14 * SN + s] = 8191 - (int)(k14 & 8191);
    ob[(size_t)15 * SN + s] = 8191 - (int)(k15 & 8191);
}

// ---------------- kernel 4: GroupNorm statistics ----------------
__global__ __launch_bounds__(256) void stats_kernel(const float* __restrict__ x,
        const int* __restrict__ knn, const float* __restrict__ w_pe,
        const float* __restrict__ w_conv, float* __restrict__ wavepart) {
    const int blk = blockIdx.x;                       // 0..255
    const int b = blockIdx.y;
    const int w = threadIdx.x >> 6, l = threadIdx.x & 63;
    float wr[10];
#pragma unroll
    for (int c = 0; c < 10; ++c) wr[c] = 0.f;
    if (l < 32) {
#pragma unroll
        for (int c = 0; c < 4; ++c) wr[c] = w_conv[l * 4 + c];
    } else {
#pragma unroll
        for (int c = 0; c < 10; ++c) wr[c] = w_pe[(l - 32) * 10 + c];
    }
    const float* xb = x + (size_t)b * 4 * PN;
    const int* kb = knn + (size_t)b * (SN * KNB);
    float s1 = 0.f, s2 = 0.f;
    const int nbase = blk * 512 + w * 128;
#pragma unroll 2
    for (int it = 0; it < 128; ++it) {
        int n = nbase + it;
        int i  = kb[n];
        int i0 = kb[n & ~15];
        float xa0 = xb[i], xa1 = xb[PN + i], xa2 = xb[2 * PN + i], xa3 = xb[3 * PN + i];
        float xc0 = xb[i0], xc1 = xb[PN + i0], xc2 = xb[2 * PN + i0];
        float d0 = xa0 - xc0, d1 = xa1 - xc1, d2 = xa2 - xc2;
        float dd = d0 * d0; dd += d1 * d1; dd += d2 * d2;
        float temp = sqrtf(fmaxf(dd, 1e-12f));
        float r;
        if (l < 32) {
            r = wr[0] * xa0 + wr[1] * xa1 + wr[2] * xa2 + wr[3] * xa3;
        } else {
            r = wr[0] * xa0 + wr[1] * xa1 + wr[2] * xa2
              + wr[3] * xc0 + wr[4] * xc1 + wr[5] * xc2
              + wr[6] * d0 + wr[7] * d1 + wr[8] * d2 + wr[9] * temp;
        }
        s1 += r;
        s2 += r * r;
    }
    const int wslot = blk * 4 + w;                    // 0..1023
    wavepart[((size_t)b * 1024 + wslot) * 128 + l] = s1;
    wavepart[((size_t)b * 1024 + wslot) * 128 + 64 + l] = s2;
}

// ---------------- kernel 5: finalize stats -> per-channel scale/shift ----------------
__global__ void finalize_kernel(const float* __restrict__ wavepart,
        const float* __restrict__ g_pe, const float* __restrict__ b_pe,
        const float* __restrict__ g_conv, const float* __restrict__ b_conv,
        float* __restrict__ scsh) {
    const int t = threadIdx.x;                        // 0..255
    const int b = t >> 7, k = t & 127;
    float acc = 0.f;
    for (int w = 0; w < 1024; ++w) acc += wavepart[((size_t)b * 1024 + w) * 128 + k];
    __shared__ float sums[2][128];
    sums[b][k] = acc;
    __syncthreads();
    if (k < 64) {
        const float N = 131072.f;
        float mean = sums[b][k] / N;
        float var = sums[b][64 + k] / N - mean * mean;
        float rstd = 1.0f / sqrtf(var + 1e-5f);
        float gam = (k < 32) ? g_conv[k] : g_pe[k - 32];
        float bet = (k < 32) ? b_conv[k] : b_pe[k - 32];
        float sc = gam * rstd;
        scsh[(b * 64 + k) * 2 + 0] = sc;
        scsh[(b * 64 + k) * 2 + 1] = bet - mean * sc;
    }
}

// ---------------- kernel 6: fused feature/attention/output ----------------
__global__ __launch_bounds__(256) void fused_main_kernel(
        const float* __restrict__ x, const int* __restrict__ knn,
        const float* __restrict__ w_pe, const float* __restrict__ w_conv,
        const float* __restrict__ w_att1, const float* __restrict__ w_att2,
        const float* __restrict__ w_b1, const float* __restrict__ w_b2,
        const float* __restrict__ scsh, float* __restrict__ out) {
    __shared__ float wb1T[64 * 64];                   // [c][o]
    __shared__ float wb2T[4 * 64];                    // [c][o]
    for (int i = threadIdx.x; i < 64 * 64; i += 256) wb1T[(i & 63) * 64 + (i >> 6)] = w_b1[i];
    { int i = threadIdx.x; wb2T[(i & 3) * 64 + (i >> 2)] = w_b2[i]; }
    __syncthreads();
    const int gidx = blockIdx.x;                      // 0..1023
    const int b = gidx >> 9;
    const int sb = (gidx & 511) << 4;
    const int l = threadIdx.x & 63;
    const int w = threadIdx.x >> 6;
    const int g = l >> 4, j = l & 15;
    const int s = sb + (w << 2) + g;
    const int srcl = g << 4;
    const float* xb = x + (size_t)b * 4 * PN;
    const int i1 = knn[(size_t)b * (SN * KNB) + (size_t)s * KNB + j];
    float xa0 = xb[i1], xa1 = xb[PN + i1], xa2 = xb[2 * PN + i1], xa3 = xb[3 * PN + i1];
    float xc0 = __shfl(xa0, srcl), xc1 = __shfl(xa1, srcl);
    float xc2 = __shfl(xa2, srcl), xc3 = __shfl(xa3, srcl);
    float d0 = xa0 - xc0, d1 = xa1 - xc1, d2 = xa2 - xc2;
    float dd = d0 * d0; dd += d1 * d1; dd += d2 * d2;
    float temp = sqrtf(fmaxf(dd, 1e-12f));
    float pem[10] = {xa0, xa1, xa2, xc0, xc1, xc2, d0, d1, d2, temp};
    float f[64];
    const float* ssb = scsh + b * 128;
#pragma unroll
    for (int o = 0; o < 32; ++o) {
        float r = w_conv[o * 4 + 0] * xa0;
        r += w_conv[o * 4 + 1] * xa1;
        r += w_conv[o * 4 + 2] * xa2;
        r += w_conv[o * 4 + 3] * xa3;
        r = r * ssb[o * 2 + 0] + ssb[o * 2 + 1];
        f[o] = (r >= 0.f) ? r : 0.2f * r;
    }
#pragma unroll
    for (int o = 0; o < 32; ++o) {
        float r = 0.f;
#pragma unroll
        for (int c = 0; c < 10; ++c) r += w_pe[o * 10 + c] * pem[c];
        r = r * ssb[(32 + o) * 2 + 0] + ssb[(32 + o) * 2 + 1];
        f[32 + o] = (r >= 0.f) ? r : 0.2f * r;
    }
    float logit = 0.f;
#pragma unroll 2
    for (int o = 0; o < 32; ++o) {
        float a = 0.f;
#pragma unroll
        for (int c = 0; c < 64; ++c) a += w_att1[o * 64 + c] * f[c];
        a = (a >= 0.f) ? a : 0.2f * a;
        logit += w_att2[o] * a;
    }
    float mx = logit;
    mx = fmaxf(mx, __shfl_xor(mx, 1));
    mx = fmaxf(mx, __shfl_xor(mx, 2));
    mx = fmaxf(mx, __shfl_xor(mx, 4));
    mx = fmaxf(mx, __shfl_xor(mx, 8));
    float e = expf(logit - mx);
    float se = e;
    se += __shfl_xor(se, 1);
    se += __shfl_xor(se, 2);
    se += __shfl_xor(se, 4);
    se += __shfl_xor(se, 8);
    float att = e / se;
#pragma unroll
    for (int c = 0; c < 64; ++c) {
        float v = f[c] * att;
        v += __shfl_xor(v, 1);
        v += __shfl_xor(v, 2);
        v += __shfl_xor(v, 4);
        v += __shfl_xor(v, 8);
        f[c] = v;
    }
    float o0 = 0.f, o1 = 0.f, o2 = 0.f, o3 = 0.f;
#pragma unroll
    for (int c = 0; c < 64; ++c) {
        float4 wv = *reinterpret_cast<const float4*>(&wb1T[c * 64 + 4 * j]);
        o0 += wv.x * f[c]; o1 += wv.y * f[c]; o2 += wv.z * f[c]; o3 += wv.w * f[c];
    }
    {
        float4 wv = *reinterpret_cast<const float4*>(&wb2T[0 * 64 + 4 * j]);
        o0 += wv.x * xc0; o1 += wv.y * xc0; o2 += wv.z * xc0; o3 += wv.w * xc0;
        wv = *reinterpret_cast<const float4*>(&wb2T[1 * 64 + 4 * j]);
        o0 += wv.x * xc1; o1 += wv.y * xc1; o2 += wv.z * xc1; o3 += wv.w * xc1;
        wv = *reinterpret_cast<const float4*>(&wb2T[2 * 64 + 4 * j]);
        o0 += wv.x * xc2; o1 += wv.y * xc2; o2 += wv.z * xc2; o3 += wv.w * xc2;
        wv = *reinterpret_cast<const float4*>(&wb2T[3 * 64 + 4 * j]);
        o0 += wv.x * xc3; o1 += wv.y * xc3; o2 += wv.z * xc3; o3 += wv.w * xc3;
    }
    o0 = (o0 >= 0.f) ? o0 : 0.1f * o0;
    o1 = (o1 >= 0.f) ? o1 : 0.1f * o1;
    o2 = (o2 >= 0.f) ? o2 : 0.1f * o2;
    o3 = (o3 >= 0.f) ? o3 : 0.1f * o3;
    float* ob = out + (size_t)b * 67 * SN;
    const int oc = 3 + 4 * j;
    ob[(size_t)(oc + 0) * SN + s] = o0;
    ob[(size_t)(oc + 1) * SN + s] = o1;
    ob[(size_t)(oc + 2) * SN + s] = o2;
    ob[(size_t)(oc + 3) * SN + s] = o3;
    if (j < 3) ob[(size_t)j * SN + s] = (j == 0) ? xc0 : ((j == 1) ? xc1 : xc2);
}

extern "C" void kernel_launch(void* const* d_in, const int* in_sizes, int n_in,
                              void* d_out, int out_size, void* d_ws, size_t ws_size,
                              hipStream_t stream) {
    (void)in_sizes; (void)n_in; (void)out_size; (void)ws_size;
    const float* x      = (const float*)d_in[0];
    const float* rnd    = (const float*)d_in[1];
    const float* w_pe   = (const float*)d_in[2];
    const float* g_pe   = (const float*)d_in[3];
    const float* b_pe   = (const float*)d_in[4];
    const float* w_conv = (const float*)d_in[5];
    const float* g_conv = (const float*)d_in[6];
    const float* b_conv = (const float*)d_in[7];
    const float* w_att1 = (const float*)d_in[8];
    const float* w_att2 = (const float*)d_in[9];
    const float* w_b1   = (const float*)d_in[10];
    const float* w_b2   = (const float*)d_in[11];
    float* out = (float*)d_out;
    char* ws = (char*)d_ws;
    // workspace carve-up (bytes), peak ~10.09 MB (< proven 10.81 MB).
    // Region A [327680, 8716288) = 8 MB, time-shared sequentially:
    //   rcnt (256K; rank_count->scatter) -> vv (8MB; K1->K1.5)
    //   -> segIdx (8MB exactly; collect->exact) -> wavept (1MB; stats->finalize)
    float4*         pts    = (float4*)        (ws + 0);          //   262,144
    int*            perm   = (int*)           (ws + 262144);     //    65,536
    unsigned short* rcnt   = (unsigned short*)(ws + 327680);     //   262,144 (A)
    float*          vv     = (float*)         (ws + 327680);     // 8,388,608 (A)
    unsigned short* segIdx = (unsigned short*)(ws + 327680);     // 8,388,608 (A) 16384*8*32*2
    float*          wavept = (float*)         (ws + 327680);     // 1,048,576 (A)
    float*          thrbuf = (float*)         (ws + 8716288);    //    65,536
    unsigned short* segcnt = (unsigned short*)(ws + 8781824);    //   262,144
    int*            knn    = (int*)           (ws + 9043968);    // 1,048,576
    float*          scsh   = (float*)         (ws + 10092544);   //     1,024

    pack_pts_kernel<<<64, 256, 0, stream>>>(x, pts);
    rank_count_kernel<<<dim3(NRCH, 32, 2), 256, 0, stream>>>(rnd, rcnt);
    rank_scatter_kernel<<<64, 256, 0, stream>>>(rcnt, perm);
    knn_val16_kernel<<<dim3(NCH1, 32, 2), 256, 0, stream>>>(pts, perm, vv);
    knn_thr_kernel<<<64, 256, 0, stream>>>(vv, thrbuf);
    knn_collect_kernel<<<dim3(NCOL, 32, 2), 256, 0, stream>>>(pts, perm, thrbuf, segcnt, segIdx);
    knn_exact_kernel<<<64, 256, 0, stream>>>(pts, perm, segcnt, segIdx, knn);
    stats_kernel<<<dim3(256, 2), 256, 0, stream>>>(x, knn, w_pe, w_conv, wavept);
    finalize_kernel<<<1, 256, 0, stream>>>(wavept, g_pe, b_pe, g_conv, b_conv, scsh);
    fused_main_kernel<<<1024, 256, 0, stream>>>(x, knn, w_pe, w_conv, w_att1, w_att2,
                                                w_b1, w_b2, scsh, out);
}

// Round 15
// 351.015 us; speedup vs baseline: 1.1351x; 1.0107x over previous
//
#include <hip/hip_runtime.h>
#include <stdint.h>

#define PN 8192
#define SN 8192
#define KNB 16
#define SUBS 4                 // threshold subsample stride -> 2048 candidates
#define NCH1 8
#define CHUNK1 256             // subsample candidates per chunk
#define NCOL 4
#define COLCH (PN / NCOL)      // 2048 candidates per chunk
#define SCAP 56                // LDS queue cap: lambda=16, P(>56)~1e-13/seg
#define MARGIN 1.0e-3f
#define NRCH 8
#define RCH (PN / NRCH)        // 1024

#define KEY_SENTINEL ((long long)0x8000000000000000ULL)
#define PD_SCALE 2199023255552.0   // 2^41: dd<1024 -> |scaled|<2^51; <<13 fits i64

// ---------------- helpers: branch-free sorted-16 maintenance ----------------
__device__ __forceinline__ void bitonic_sort16(float* b) {
#pragma unroll
    for (int k = 2; k <= 16; k <<= 1) {
#pragma unroll
        for (int j = k >> 1; j > 0; j >>= 1) {
#pragma unroll
            for (int i = 0; i < 16; ++i) {
                int l = i ^ j;
                if (l > i) {
                    float lo = fminf(b[i], b[l]), hi = fmaxf(b[i], b[l]);
                    bool up = ((i & k) == 0);
                    b[i] = up ? lo : hi;
                    b[l] = up ? hi : lo;
                }
            }
        }
    }
}
// r, b ascending sorted-16 -> r = lowest 16 of union, ascending.
__device__ __forceinline__ void merge16(float* r, const float* b) {
    float t[16];
#pragma unroll
    for (int i = 0; i < 16; ++i) t[i] = fminf(r[i], b[15 - i]);   // bitonic
#pragma unroll
    for (int j = 8; j > 0; j >>= 1) {
#pragma unroll
        for (int i = 0; i < 16; ++i) {
            int l = i ^ j;
            if (l > i) {
                float lo = fminf(t[i], t[l]), hi = fmaxf(t[i], t[l]);
                t[i] = lo; t[l] = hi;
            }
        }
    }
#pragma unroll
    for (int i = 0; i < 16; ++i) r[i] = t[i];
}

// ---------------- kernel 0: pack points (x,y,z,0) ----------------
__global__ void pack_pts_kernel(const float* __restrict__ x, float4* __restrict__ pts) {
    int i = blockIdx.x * 256 + threadIdx.x;           // 0 .. 2*PN-1
    int b = i >> 13, p = i & (PN - 1);
    const float* xb = x + (size_t)b * 4 * PN;
    pts[i] = make_float4(xb[p], xb[PN + p], xb[2 * PN + p], 0.f);
}

// ---------------- argsort stage A: partial rank counts (rank-by-counting) ----------------
__global__ __launch_bounds__(256) void rank_count_kernel(const float* __restrict__ rnd,
        unsigned short* __restrict__ rcnt) {
    __shared__ unsigned long long lk[RCH];            // 8 KB
    const int chunk = blockIdx.x, sg = blockIdx.y, b = blockIdx.z;
    const unsigned int* rb = (const unsigned int*)rnd + b * PN;   // [0,1) floats: bits order-preserving
    const int cbase = chunk * RCH;
    for (int c = threadIdx.x; c < RCH; c += 256) {
        int j = cbase + c;
        lk[c] = ((unsigned long long)rb[j] << 13) | (unsigned)j;
    }
    __syncthreads();
    const int i = sg * 256 + threadIdx.x;
    const unsigned long long ki = ((unsigned long long)rb[i] << 13) | (unsigned)i;
    int cnt = 0;
#pragma unroll 8
    for (int c = 0; c < RCH; ++c) cnt += (lk[c] < ki) ? 1 : 0;
    rcnt[(((size_t)(b * NRCH + chunk)) << 13) + i] = (unsigned short)cnt;
}

// ---------------- argsort stage B: sum partials, scatter perm[rank] = i ----------------
__global__ void rank_scatter_kernel(const unsigned short* __restrict__ rcnt,
                                    int* __restrict__ perm) {
    int t = blockIdx.x * 256 + threadIdx.x;           // 0 .. 2*PN-1
    int b = t >> 13, i = t & (PN - 1);
    int rank = 0;
#pragma unroll
    for (int ch = 0; ch < NRCH; ++ch)
        rank += rcnt[(((size_t)(b * NRCH + ch)) << 13) + i];
    perm[b * PN + rank] = i;
}

// ---------------- K1: per-(sample, subsample-chunk) sorted f32 top-16 distances ----------------
// Candidate stream is wave-uniform -> read straight from global (scalar-load path).
// Stride-4 SUBSAMPLE: subset's 16th order stat >= true d16.
__global__ __launch_bounds__(256) void knn_val16_kernel(const float4* __restrict__ pts,
        const int* __restrict__ perm, float* __restrict__ vv) {
    const int chunk = blockIdx.x, sg = blockIdx.y, b = blockIdx.z;
    const float4* pb = pts + b * PN;
    const int pbase = chunk * CHUNK1;
    const int s = sg * 256 + threadIdx.x;
    const float4 qp = pb[perm[b * PN + s]];
    float r[16];
#pragma unroll
    for (int i = 0; i < 16; ++i) r[i] = 3.0e38f;
    for (int t = 0; t < CHUNK1; t += 16) {
        float bv[16];
#pragma unroll
        for (int u = 0; u < 16; ++u) {
            float4 pp = pb[SUBS * (pbase + t + u)];   // uniform addr -> s_load
            float dx = qp.x - pp.x, dy = qp.y - pp.y, dz = qp.z - pp.z;
            bv[u] = dx * dx + dy * dy + dz * dz;
        }
        bitonic_sort16(bv);
        merge16(r, bv);
    }
    float* ov = vv + ((size_t)(b * NCH1 + chunk) * 16) * SN + s;
#pragma unroll
    for (int i = 0; i < 16; ++i) ov[(size_t)i * SN] = r[i];
}

// ---------------- K1.5: merge 8 sorted chunk value-lists -> subsample d16 -> thr ----------------
__global__ void knn_thr_kernel(const float* __restrict__ vv, float* __restrict__ thrbuf) {
    int t = blockIdx.x * 256 + threadIdx.x;           // 0 .. 2*SN-1
    int b = t >> 13, s = t & (SN - 1);
    float r[16], bl[16];
    const float* v0 = vv + ((size_t)(b * NCH1) * 16) * SN + s;
#pragma unroll
    for (int i = 0; i < 16; ++i) r[i] = v0[(size_t)i * SN];
    for (int ch = 1; ch < NCH1; ++ch) {
        const float* vc = vv + ((size_t)(b * NCH1 + ch) * 16) * SN + s;
#pragma unroll
        for (int i = 0; i < 16; ++i) bl[i] = vc[(size_t)i * SN];
        merge16(r, bl);
    }
    thrbuf[b * SN + s] = r[15] + MARGIN;              // >= true global d16 (subset bound)
}

// ---------------- K2: fused collect + exact top-16 per (sample, chunk) ----------------
// Phase A: round-13-proven 8-wide pipelined scan (NAMED float4 regs, >=8 loads in
// flight) -> survivors into a block-local LDS queue (no global indirection at all).
// Phase B: read survivors from LDS (warm), gather pts from the block's own warm L2,
// exact f64 keys into 16 NAMED i64 regs via the round-13 INS16 network.
// Output: per-chunk sorted 16 keys -> partK. Overflow (P~1e-7): exact full rescan.
#define MAKEKEY(pp, c, out) do { \
    double dx_ = qx - (double)(pp).x; \
    double dy_ = qy - (double)(pp).y; \
    double dz_ = qz - (double)(pp).z; \
    double dd_ = dx_ * dx_ + dy_ * dy_ + dz_ * dz_; \
    long long sc_ = (long long)floor(-dd_ * PD_SCALE); \
    (out) = (sc_ << 13) | (long long)(8191 - (c)); \
} while (0)

#define INS16(kkv) do { long long nk = (kkv); if (nk > k15) { \
    k15 = (nk > k14) ? k14 : ((nk > k15) ? nk : k15); \
    k14 = (nk > k13) ? k13 : ((nk > k14) ? nk : k14); \
    k13 = (nk > k12) ? k12 : ((nk > k13) ? nk : k13); \
    k12 = (nk > k11) ? k11 : ((nk > k12) ? nk : k12); \
    k11 = (nk > k10) ? k10 : ((nk > k11) ? nk : k11); \
    k10 = (nk > k9 ) ? k9  : ((nk > k10) ? nk : k10); \
    k9  = (nk > k8 ) ? k8  : ((nk > k9 ) ? nk : k9 ); \
    k8  = (nk > k7 ) ? k7  : ((nk > k8 ) ? nk : k8 ); \
    k7  = (nk > k6 ) ? k6  : ((nk > k7 ) ? nk : k7 ); \
    k6  = (nk > k5 ) ? k5  : ((nk > k6 ) ? nk : k6 ); \
    k5  = (nk > k4 ) ? k4  : ((nk > k5 ) ? nk : k5 ); \
    k4  = (nk > k3 ) ? k3  : ((nk > k4 ) ? nk : k4 ); \
    k3  = (nk > k2 ) ? k2  : ((nk > k3 ) ? nk : k3 ); \
    k2  = (nk > k1 ) ? k1  : ((nk > k2 ) ? nk : k2 ); \
    k1  = (nk > k0 ) ? k0  : ((nk > k1 ) ? nk : k1 ); \
    k0  = (nk > k0 ) ? nk  : k0; \
} } while (0)

#define QPROC(pp, cidx) do { \
    float dx_ = qp.x - (pp).x, dy_ = qp.y - (pp).y, dz_ = qp.z - (pp).z; \
    float dd_ = dx_ * dx_; dd_ += dy_ * dy_; dd_ += dz_ * dz_; \
    if (dd_ < thr) { if (cnt < SCAP) surv[cnt][tid] = (unsigned short)(cidx); ++cnt; } \
} while (0)

__global__ __launch_bounds__(256) void knn_chunk_kernel(const float4* __restrict__ pts,
        const int* __restrict__ perm, const float* __restrict__ thrbuf,
        long long* __restrict__ partK) {
    __shared__ unsigned short surv[SCAP][256];        // 28 KB ([u][tid]: conflict-free)
    const int chunk = blockIdx.x, sg = blockIdx.y, b = blockIdx.z;
    const float4* pb = pts + b * PN;
    const int pbase = chunk * COLCH;
    const int tid = threadIdx.x;
    const int s = sg * 256 + tid;
    const int bs = b * SN + s;
    const float4 qp = pb[perm[bs]];
    const float thr = thrbuf[bs];
    int cnt = 0;
    const float4* cp = pb + pbase;
    // ---- phase A: pipelined scan -> LDS survivor queue ----
    float4 a0 = cp[0], a1 = cp[1], a2 = cp[2], a3 = cp[3];
    float4 a4 = cp[4], a5 = cp[5], a6 = cp[6], a7 = cp[7];
    int c = 0;
    for (; c < COLCH - 8; c += 8) {
        float4 n0 = cp[c + 8],  n1 = cp[c + 9],  n2 = cp[c + 10], n3 = cp[c + 11];
        float4 n4 = cp[c + 12], n5 = cp[c + 13], n6 = cp[c + 14], n7 = cp[c + 15];
        QPROC(a0, pbase + c + 0);
        QPROC(a1, pbase + c + 1);
        QPROC(a2, pbase + c + 2);
        QPROC(a3, pbase + c + 3);
        QPROC(a4, pbase + c + 4);
        QPROC(a5, pbase + c + 5);
        QPROC(a6, pbase + c + 6);
        QPROC(a7, pbase + c + 7);
        a0 = n0; a1 = n1; a2 = n2; a3 = n3;
        a4 = n4; a5 = n5; a6 = n6; a7 = n7;
    }
    QPROC(a0, pbase + c + 0);
    QPROC(a1, pbase + c + 1);
    QPROC(a2, pbase + c + 2);
    QPROC(a3, pbase + c + 3);
    QPROC(a4, pbase + c + 4);
    QPROC(a5, pbase + c + 5);
    QPROC(a6, pbase + c + 6);
    QPROC(a7, pbase + c + 7);
    // ---- phase B: exact f64 keys over survivors ----
    const double qx = qp.x, qy = qp.y, qz = qp.z;
    long long k0 = KEY_SENTINEL, k1 = KEY_SENTINEL, k2 = KEY_SENTINEL, k3 = KEY_SENTINEL,
              k4 = KEY_SENTINEL, k5 = KEY_SENTINEL, k6 = KEY_SENTINEL, k7 = KEY_SENTINEL,
              k8 = KEY_SENTINEL, k9 = KEY_SENTINEL, k10 = KEY_SENTINEL, k11 = KEY_SENTINEL,
              k12 = KEY_SENTINEL, k13 = KEY_SENTINEL, k14 = KEY_SENTINEL, k15 = KEY_SENTINEL;
    if (cnt <= SCAP) {
        for (int u = 0; u < cnt; u += 4) {
            int c0i = surv[u][tid];                   // LDS, warm, conflict-free
            int c1i = (u + 1 < cnt) ? (int)surv[u + 1][tid] : 0;
            int c2i = (u + 2 < cnt) ? (int)surv[u + 2][tid] : 0;
            int c3i = (u + 3 < cnt) ? (int)surv[u + 3][tid] : 0;
            float4 p0 = pb[c0i], p1 = pb[c1i], p2 = pb[c2i], p3 = pb[c3i];  // warm L2
            long long kk0, kk1, kk2, kk3;
            MAKEKEY(p0, c0i, kk0);
            MAKEKEY(p1, c1i, kk1);
            MAKEKEY(p2, c2i, kk2);
            MAKEKEY(p3, c3i, kk3);
            kk1 = (u + 1 < cnt) ? kk1 : KEY_SENTINEL;
            kk2 = (u + 2 < cnt) ? kk2 : KEY_SENTINEL;
            kk3 = (u + 3 < cnt) ? kk3 : KEY_SENTINEL;
            INS16(kk0);
            INS16(kk1);
            INS16(kk2);
            INS16(kk3);
        }
    } else {
        // deterministic exact fallback (P ~ 1e-7): full chunk rescan
        for (int cc = 0; cc < COLCH; ++cc) {
            float4 pp = cp[cc];
            long long kk;
            MAKEKEY(pp, pbase + cc, kk);
            INS16(kk);
        }
    }
    long long* ok = partK + ((size_t)(b * NCOL + chunk) * SN + s) * KNB;
    ok[0]  = k0;  ok[1]  = k1;  ok[2]  = k2;  ok[3]  = k3;
    ok[4]  = k4;  ok[5]  = k5;  ok[6]  = k6;  ok[7]  = k7;
    ok[8]  = k8;  ok[9]  = k9;  ok[10] = k10; ok[11] = k11;
    ok[12] = k12; ok[13] = k13; ok[14] = k14; ok[15] = k15;
}

// ---------------- K3: merge 4 sorted chunk-lists, write knn[b][rank][s] ----------------
// Keys are unique (index embedded); pop-max 4-way merge, deterministic.
__global__ void knn_merge_kernel(const long long* __restrict__ partK, int* __restrict__ knn) {
    int t = blockIdx.x * 64 + threadIdx.x;            // 0 .. 2*SN-1, 256 blocks
    int b = t >> 13, s = t & (SN - 1);
    const long long* K0 = partK + ((size_t)(b * NCOL + 0) * SN + s) * KNB;
    const long long* K1 = partK + ((size_t)(b * NCOL + 1) * SN + s) * KNB;
    const long long* K2 = partK + ((size_t)(b * NCOL + 2) * SN + s) * KNB;
    const long long* K3 = partK + ((size_t)(b * NCOL + 3) * SN + s) * KNB;
    long long h0 = K0[0], h1 = K1[0], h2 = K2[0], h3 = K3[0];
    int p0 = 1, p1 = 1, p2 = 1, p3 = 1;
    int* ob = knn + (size_t)b * (SN * KNB);
    for (int r = 0; r < KNB; ++r) {
        long long m01 = h0 > h1 ? h0 : h1;
        long long m23 = h2 > h3 ? h2 : h3;
        long long m = m01 > m23 ? m01 : m23;
        ob[(size_t)r * SN + s] = 8191 - (int)(m & 8191);
        if (m == h0)      { h0 = (p0 < KNB) ? K0[p0] : KEY_SENTINEL; ++p0; }
        else if (m == h1) { h1 = (p1 < KNB) ? K1[p1] : KEY_SENTINEL; ++p1; }
        else if (m == h2) { h2 = (p2 < KNB) ? K2[p2] : KEY_SENTINEL; ++p2; }
        else              { h3 = (p3 < KNB) ? K3[p3] : KEY_SENTINEL; ++p3; }
    }
}

// ---------------- kernel 4: GroupNorm statistics ----------------
__global__ __launch_bounds__(256) void stats_kernel(const float* __restrict__ x,
        const int* __restrict__ knn, const float* __restrict__ w_pe,
        const float* __restrict__ w_conv, float* __restrict__ wavepart) {
    const int blk = blockIdx.x;                       // 0..255
    const int b = blockIdx.y;
    const int w = threadIdx.x >> 6, l = threadIdx.x & 63;
    float wr[10];
#pragma unroll
    for (int c = 0; c < 10; ++c) wr[c] = 0.f;
    if (l < 32) {
#pragma unroll
        for (int c = 0; c < 4; ++c) wr[c] = w_conv[l * 4 + c];
    } else {
#pragma unroll
        for (int c = 0; c < 10; ++c) wr[c] = w_pe[(l - 32) * 10 + c];
    }
    const float* xb = x + (size_t)b * 4 * PN;
    const int* kb = knn + (size_t)b * (SN * KNB);
    float s1 = 0.f, s2 = 0.f;
    const int nbase = blk * 512 + w * 128;
#pragma unroll 2
    for (int it = 0; it < 128; ++it) {
        int n = nbase + it;
        int i  = kb[n];
        int i0 = kb[n & ~15];
        float xa0 = xb[i], xa1 = xb[PN + i], xa2 = xb[2 * PN + i], xa3 = xb[3 * PN + i];
        float xc0 = xb[i0], xc1 = xb[PN + i0], xc2 = xb[2 * PN + i0];
        float d0 = xa0 - xc0, d1 = xa1 - xc1, d2 = xa2 - xc2;
        float dd = d0 * d0; dd += d1 * d1; dd += d2 * d2;
        float temp = sqrtf(fmaxf(dd, 1e-12f));
        float r;
        if (l < 32) {
            r = wr[0] * xa0 + wr[1] * xa1 + wr[2] * xa2 + wr[3] * xa3;
        } else {
            r = wr[0] * xa0 + wr[1] * xa1 + wr[2] * xa2
              + wr[3] * xc0 + wr[4] * xc1 + wr[5] * xc2
              + wr[6] * d0 + wr[7] * d1 + wr[8] * d2 + wr[9] * temp;
        }
        s1 += r;
        s2 += r * r;
    }
    const int wslot = blk * 4 + w;                    // 0..1023
    wavepart[((size_t)b * 1024 + wslot) * 128 + l] = s1;
    wavepart[((size_t)b * 1024 + wslot) * 128 + 64 + l] = s2;
}

// ---------------- kernel 5: finalize stats -> per-channel scale/shift ----------------
__global__ void finalize_kernel(const float* __restrict__ wavepart,
        const float* __restrict__ g_pe, const float* __restrict__ b_pe,
        const float* __restrict__ g_conv, const float* __restrict__ b_conv,
        float* __restrict__ scsh) {
    const int t = threadIdx.x;                        // 0..255
    const int b = t >> 7, k = t & 127;
    float acc = 0.f;
    for (int w = 0; w < 1024; ++w) acc += wavepart[((size_t)b * 1024 + w) * 128 + k];
    __shared__ float sums[2][128];
    sums[b][k] = acc;
    __syncthreads();
    if (k < 64) {
        const float N = 131072.f;
        float mean = sums[b][k] / N;
        float var = sums[b][64 + k] / N - mean * mean;
        float rstd = 1.0f / sqrtf(var + 1e-5f);
        float gam = (k < 32) ? g_conv[k] : g_pe[k - 32];
        float bet = (k < 32) ? b_conv[k] : b_pe[k - 32];
        float sc = gam * rstd;
        scsh[(b * 64 + k) * 2 + 0] = sc;
        scsh[(b * 64 + k) * 2 + 1] = bet - mean * sc;
    }
}

// ---------------- kernel 6: fused feature/attention/output ----------------
__global__ __launch_bounds__(256) void fused_main_kernel(
        const float* __restrict__ x, const int* __restrict__ knn,
        const float* __restrict__ w_pe, const float* __restrict__ w_conv,
        const float* __restrict__ w_att1, const float* __restrict__ w_att2,
        const float* __restrict__ w_b1, const float* __restrict__ w_b2,
        const float* __restrict__ scsh, float* __restrict__ out) {
    __shared__ float wb1T[64 * 64];                   // [c][o]
    __shared__ float wb2T[4 * 64];                    // [c][o]
    for (int i = threadIdx.x; i < 64 * 64; i += 256) wb1T[(i & 63) * 64 + (i >> 6)] = w_b1[i];
    { int i = threadIdx.x; wb2T[(i & 3) * 64 + (i >> 2)] = w_b2[i]; }
    __syncthreads();
    const int gidx = blockIdx.x;                      // 0..1023
    const int b = gidx >> 9;
    const int sb = (gidx & 511) << 4;
    const int l = threadIdx.x & 63;
    const int w = threadIdx.x >> 6;
    const int g = l >> 4, j = l & 15;
    const int s = sb + (w << 2) + g;
    const int srcl = g << 4;
    const float* xb = x + (size_t)b * 4 * PN;
    const int i1 = knn[(size_t)b * (SN * KNB) + (size_t)s * KNB + j];
    float xa0 = xb[i1], xa1 = xb[PN + i1], xa2 = xb[2 * PN + i1], xa3 = xb[3 * PN + i1];
    float xc0 = __shfl(xa0, srcl), xc1 = __shfl(xa1, srcl);
    float xc2 = __shfl(xa2, srcl), xc3 = __shfl(xa3, srcl);
    float d0 = xa0 - xc0, d1 = xa1 - xc1, d2 = xa2 - xc2;
    float dd = d0 * d0; dd += d1 * d1; dd += d2 * d2;
    float temp = sqrtf(fmaxf(dd, 1e-12f));
    float pem[10] = {xa0, xa1, xa2, xc0, xc1, xc2, d0, d1, d2, temp};
    float f[64];
    const float* ssb = scsh + b * 128;
#pragma unroll
    for (int o = 0; o < 32; ++o) {
        float r = w_conv[o * 4 + 0] * xa0;
        r += w_conv[o * 4 + 1] * xa1;
        r += w_conv[o * 4 + 2] * xa2;
        r += w_conv[o * 4 + 3] * xa3;
        r = r * ssb[o * 2 + 0] + ssb[o * 2 + 1];
        f[o] = (r >= 0.f) ? r : 0.2f * r;
    }
#pragma unroll
    for (int o = 0; o < 32; ++o) {
        float r = 0.f;
#pragma unroll
        for (int c = 0; c < 10; ++c) r += w_pe[o * 10 + c] * pem[c];
        r = r * ssb[(32 + o) * 2 + 0] + ssb[(32 + o) * 2 + 1];
        f[32 + o] = (r >= 0.f) ? r : 0.2f * r;
    }
    float logit = 0.f;
#pragma unroll 2
    for (int o = 0; o < 32; ++o) {
        float a = 0.f;
#pragma unroll
        for (int c = 0; c < 64; ++c) a += w_att1[o * 64 + c] * f[c];
        a = (a >= 0.f) ? a : 0.2f * a;
        logit += w_att2[o] * a;
    }
    float mx = logit;
    mx = fmaxf(mx, __shfl_xor(mx, 1));
    mx = fmaxf(mx, __shfl_xor(mx, 2));
    mx = fmaxf(mx, __shfl_xor(mx, 4));
    mx = fmaxf(mx, __shfl_xor(mx, 8));
    float e = expf(logit - mx);
    float se = e;
    se += __shfl_xor(se, 1);
    se += __shfl_xor(se, 2);
    se += __shfl_xor(se, 4);
    se += __shfl_xor(se, 8);
    float att = e / se;
#pragma unroll
    for (int c = 0; c < 64; ++c) {
        float v = f[c] * att;
        v += __shfl_xor(v, 1);
        v += __shfl_xor(v, 2);
        v += __shfl_xor(v, 4);
        v += __shfl_xor(v, 8);
        f[c] = v;
    }
    float o0 = 0.f, o1 = 0.f, o2 = 0.f, o3 = 0.f;
#pragma unroll
    for (int c = 0; c < 64; ++c) {
        float4 wv = *reinterpret_cast<const float4*>(&wb1T[c * 64 + 4 * j]);
        o0 += wv.x * f[c]; o1 += wv.y * f[c]; o2 += wv.z * f[c]; o3 += wv.w * f[c];
    }
    {
        float4 wv = *reinterpret_cast<const float4*>(&wb2T[0 * 64 + 4 * j]);
        o0 += wv.x * xc0; o1 += wv.y * xc0; o2 += wv.z * xc0; o3 += wv.w * xc0;
        wv = *reinterpret_cast<const float4*>(&wb2T[1 * 64 + 4 * j]);
        o0 += wv.x * xc1; o1 += wv.y * xc1; o2 += wv.z * xc1; o3 += wv.w * xc1;
        wv = *reinterpret_cast<const float4*>(&wb2T[2 * 64 + 4 * j]);
        o0 += wv.x * xc2; o1 += wv.y * xc2; o2 += wv.z * xc2; o3 += wv.w * xc2;
        wv = *reinterpret_cast<const float4*>(&wb2T[3 * 64 + 4 * j]);
        o0 += wv.x * xc3; o1 += wv.y * xc3; o2 += wv.z * xc3; o3 += wv.w * xc3;
    }
    o0 = (o0 >= 0.f) ? o0 : 0.1f * o0;
    o1 = (o1 >= 0.f) ? o1 : 0.1f * o1;
    o2 = (o2 >= 0.f) ? o2 : 0.1f * o2;
    o3 = (o3 >= 0.f) ? o3 : 0.1f * o3;
    float* ob = out + (size_t)b * 67 * SN;
    const int oc = 3 + 4 * j;
    ob[(size_t)(oc + 0) * SN + s] = o0;
    ob[(size_t)(oc + 1) * SN + s] = o1;
    ob[(size_t)(oc + 2) * SN + s] = o2;
    ob[(size_t)(oc + 3) * SN + s] = o3;
    if (j < 3) ob[(size_t)j * SN + s] = (j == 0) ? xc0 : ((j == 1) ? xc1 : xc2);
}

extern "C" void kernel_launch(void* const* d_in, const int* in_sizes, int n_in,
                              void* d_out, int out_size, void* d_ws, size_t ws_size,
                              hipStream_t stream) {
    (void)in_sizes; (void)n_in; (void)out_size; (void)ws_size;
    const float* x      = (const float*)d_in[0];
    const float* rnd    = (const float*)d_in[1];
    const float* w_pe   = (const float*)d_in[2];
    const float* g_pe   = (const float*)d_in[3];
    const float* b_pe   = (const float*)d_in[4];
    const float* w_conv = (const float*)d_in[5];
    const float* g_conv = (const float*)d_in[6];
    const float* b_conv = (const float*)d_in[7];
    const float* w_att1 = (const float*)d_in[8];
    const float* w_att2 = (const float*)d_in[9];
    const float* w_b1   = (const float*)d_in[10];
    const float* w_b2   = (const float*)d_in[11];
    float* out = (float*)d_out;
    char* ws = (char*)d_ws;
    // workspace carve-up (bytes), peak ~10.09 MB (< proven 10.81 MB).
    // Region A [327680, 8716288) = 8 MB, time-shared sequentially:
    //   rcnt (256K; rank_count->scatter) -> vv (8MB; K1->K1.5)
    //   -> partK (8MB exactly; knn_chunk->merge) -> wavept (1MB; stats->finalize)
    float4*         pts    = (float4*)        (ws + 0);          //   262,144
    int*            perm   = (int*)           (ws + 262144);     //    65,536
    unsigned short* rcnt   = (unsigned short*)(ws + 327680);     //   262,144 (A)
    float*          vv     = (float*)         (ws + 327680);     // 8,388,608 (A)
    long long*      partK  = (long long*)     (ws + 327680);     // 8,388,608 (A) 16384*4*16*8
    float*          wavept = (float*)         (ws + 327680);     // 1,048,576 (A)
    float*          thrbuf = (float*)         (ws + 8716288);    //    65,536
    int*            knn    = (int*)           (ws + 9043968);    // 1,048,576
    float*          scsh   = (float*)         (ws + 10092544);   //     1,024

    pack_pts_kernel<<<64, 256, 0, stream>>>(x, pts);
    rank_count_kernel<<<dim3(NRCH, 32, 2), 256, 0, stream>>>(rnd, rcnt);
    rank_scatter_kernel<<<64, 256, 0, stream>>>(rcnt, perm);
    knn_val16_kernel<<<dim3(NCH1, 32, 2), 256, 0, stream>>>(pts, perm, vv);
    knn_thr_kernel<<<64, 256, 0, stream>>>(vv, thrbuf);
    knn_chunk_kernel<<<dim3(NCOL, 32, 2), 256, 0, stream>>>(pts, perm, thrbuf, partK);
    knn_merge_kernel<<<256, 64, 0, stream>>>(partK, knn);
    stats_kernel<<<dim3(256, 2), 256, 0, stream>>>(x, knn, w_pe, w_conv, wavept);
    finalize_kernel<<<1, 256, 0, stream>>>(wavept, g_pe, b_pe, g_conv, b_conv, scsh);
    fused_main_kernel<<<1024, 256, 0, stream>>>(x, knn, w_pe, w_conv, w_att1, w_att2,
                                                w_b1, w_b2, scsh, out);
}

// Round 16
// 307.245 us; speedup vs baseline: 1.2969x; 1.1425x over previous
//
#include <hip/hip_runtime.h>
#include <stdint.h>

#define PN 8192
#define SN 8192
#define KNB 16
#define SUBS 4                 // threshold subsample stride -> 2048 candidates
#define NCH1 8
#define CHUNK1 256             // subsample candidates per chunk
#define NSCAN 8                // scan chunks of 1024
#define SCANCH (PN / NSCAN)    // 1024
#define NPAIR 4                // output chunk-pairs (partK stays 8 MB)
#define SCAP 32                // per-(sample,1024-chunk) survivors: lambda=8, P(>32)~2e-12
#define MARGIN 1.0e-3f
#define NRCH 8
#define RCH (PN / NRCH)        // 1024

#define KEY_SENTINEL ((long long)0x8000000000000000ULL)
#define PD_SCALE 2199023255552.0   // 2^41: dd<1024 -> |scaled|<2^51; <<13 fits i64

// ---------------- helpers: branch-free sorted-16 maintenance ----------------
__device__ __forceinline__ void bitonic_sort16(float* b) {
#pragma unroll
    for (int k = 2; k <= 16; k <<= 1) {
#pragma unroll
        for (int j = k >> 1; j > 0; j >>= 1) {
#pragma unroll
            for (int i = 0; i < 16; ++i) {
                int l = i ^ j;
                if (l > i) {
                    float lo = fminf(b[i], b[l]), hi = fmaxf(b[i], b[l]);
                    bool up = ((i & k) == 0);
                    b[i] = up ? lo : hi;
                    b[l] = up ? hi : lo;
                }
            }
        }
    }
}
// r, b ascending sorted-16 -> r = lowest 16 of union, ascending.
__device__ __forceinline__ void merge16(float* r, const float* b) {
    float t[16];
#pragma unroll
    for (int i = 0; i < 16; ++i) t[i] = fminf(r[i], b[15 - i]);   // bitonic
#pragma unroll
    for (int j = 8; j > 0; j >>= 1) {
#pragma unroll
        for (int i = 0; i < 16; ++i) {
            int l = i ^ j;
            if (l > i) {
                float lo = fminf(t[i], t[l]), hi = fmaxf(t[i], t[l]);
                t[i] = lo; t[l] = hi;
            }
        }
    }
#pragma unroll
    for (int i = 0; i < 16; ++i) r[i] = t[i];
}

// ---------------- kernel 0: pack points (x,y,z,0) ----------------
__global__ void pack_pts_kernel(const float* __restrict__ x, float4* __restrict__ pts) {
    int i = blockIdx.x * 256 + threadIdx.x;           // 0 .. 2*PN-1
    int b = i >> 13, p = i & (PN - 1);
    const float* xb = x + (size_t)b * 4 * PN;
    pts[i] = make_float4(xb[p], xb[PN + p], xb[2 * PN + p], 0.f);
}

// ---------------- argsort stage A: partial rank counts (rank-by-counting) ----------------
__global__ __launch_bounds__(256) void rank_count_kernel(const float* __restrict__ rnd,
        unsigned short* __restrict__ rcnt) {
    __shared__ unsigned long long lk[RCH];            // 8 KB
    const int chunk = blockIdx.x, sg = blockIdx.y, b = blockIdx.z;
    const unsigned int* rb = (const unsigned int*)rnd + b * PN;   // [0,1) floats: bits order-preserving
    const int cbase = chunk * RCH;
    for (int c = threadIdx.x; c < RCH; c += 256) {
        int j = cbase + c;
        lk[c] = ((unsigned long long)rb[j] << 13) | (unsigned)j;
    }
    __syncthreads();
    const int i = sg * 256 + threadIdx.x;
    const unsigned long long ki = ((unsigned long long)rb[i] << 13) | (unsigned)i;
    int cnt = 0;
#pragma unroll 8
    for (int c = 0; c < RCH; ++c) cnt += (lk[c] < ki) ? 1 : 0;
    rcnt[(((size_t)(b * NRCH + chunk)) << 13) + i] = (unsigned short)cnt;
}

// ---------------- argsort stage B: sum partials, scatter perm[rank] = i ----------------
__global__ void rank_scatter_kernel(const unsigned short* __restrict__ rcnt,
                                    int* __restrict__ perm) {
    int t = blockIdx.x * 256 + threadIdx.x;           // 0 .. 2*PN-1
    int b = t >> 13, i = t & (PN - 1);
    int rank = 0;
#pragma unroll
    for (int ch = 0; ch < NRCH; ++ch)
        rank += rcnt[(((size_t)(b * NRCH + ch)) << 13) + i];
    perm[b * PN + rank] = i;
}

// ---------------- K1: per-(sample, subsample-chunk) sorted f32 top-16 distances ----------------
// Candidate stream is wave-uniform -> read straight from global (scalar-load path).
// Stride-4 SUBSAMPLE: subset's 16th order stat >= true d16.
__global__ __launch_bounds__(256) void knn_val16_kernel(const float4* __restrict__ pts,
        const int* __restrict__ perm, float* __restrict__ vv) {
    const int chunk = blockIdx.x, sg = blockIdx.y, b = blockIdx.z;
    const float4* pb = pts + b * PN;
    const int pbase = chunk * CHUNK1;
    const int s = sg * 256 + threadIdx.x;
    const float4 qp = pb[perm[b * PN + s]];
    float r[16];
#pragma unroll
    for (int i = 0; i < 16; ++i) r[i] = 3.0e38f;
    for (int t = 0; t < CHUNK1; t += 16) {
        float bv[16];
#pragma unroll
        for (int u = 0; u < 16; ++u) {
            float4 pp = pb[SUBS * (pbase + t + u)];   // uniform addr -> s_load
            float dx = qp.x - pp.x, dy = qp.y - pp.y, dz = qp.z - pp.z;
            bv[u] = dx * dx + dy * dy + dz * dz;
        }
        bitonic_sort16(bv);
        merge16(r, bv);
    }
    float* ov = vv + ((size_t)(b * NCH1 + chunk) * 16) * SN + s;
#pragma unroll
    for (int i = 0; i < 16; ++i) ov[(size_t)i * SN] = r[i];
}

// ---------------- K1.5: merge 8 sorted chunk value-lists -> subsample d16 -> thr ----------------
__global__ void knn_thr_kernel(const float* __restrict__ vv, float* __restrict__ thrbuf) {
    int t = blockIdx.x * 256 + threadIdx.x;           // 0 .. 2*SN-1
    int b = t >> 13, s = t & (SN - 1);
    float r[16], bl[16];
    const float* v0 = vv + ((size_t)(b * NCH1) * 16) * SN + s;
#pragma unroll
    for (int i = 0; i < 16; ++i) r[i] = v0[(size_t)i * SN];
    for (int ch = 1; ch < NCH1; ++ch) {
        const float* vc = vv + ((size_t)(b * NCH1 + ch) * 16) * SN + s;
#pragma unroll
        for (int i = 0; i < 16; ++i) bl[i] = vc[(size_t)i * SN];
        merge16(r, bl);
    }
    thrbuf[b * SN + s] = r[15] + MARGIN;              // >= true global d16 (subset bound)
}

// ---------------- K2: fused scan + exact top-16 per (sample, chunk-PAIR) ----------------
// Block = 128 samples x 2 chunks of 1024 (t<128: chunk 2p; t>=128: chunk 2p+1).
// Grid 512 blocks -> 2-4 blocks/CU (round-15 lesson: 256 blocks = 1 wave/SIMD killed TLP).
// Phase A: round-13-proven 8-wide pipelined scan -> survivors in own LDS column.
// Phase B: exact f64 keys via INS16 named-register network (round-13-proven).
// Pair-merge: upper half posts its sorted-16 to LDS; lower half INS16-folds it ->
// top-16 of the pair -> partK (NCOL=4, 8 MB layout unchanged). Deterministic.
#define MAKEKEY(pp, c, out) do { \
    double dx_ = qx - (double)(pp).x; \
    double dy_ = qy - (double)(pp).y; \
    double dz_ = qz - (double)(pp).z; \
    double dd_ = dx_ * dx_ + dy_ * dy_ + dz_ * dz_; \
    long long sc_ = (long long)floor(-dd_ * PD_SCALE); \
    (out) = (sc_ << 13) | (long long)(8191 - (c)); \
} while (0)

#define INS16(kkv) do { long long nk = (kkv); if (nk > k15) { \
    k15 = (nk > k14) ? k14 : ((nk > k15) ? nk : k15); \
    k14 = (nk > k13) ? k13 : ((nk > k14) ? nk : k14); \
    k13 = (nk > k12) ? k12 : ((nk > k13) ? nk : k13); \
    k12 = (nk > k11) ? k11 : ((nk > k12) ? nk : k12); \
    k11 = (nk > k10) ? k10 : ((nk > k11) ? nk : k11); \
    k10 = (nk > k9 ) ? k9  : ((nk > k10) ? nk : k10); \
    k9  = (nk > k8 ) ? k8  : ((nk > k9 ) ? nk : k9 ); \
    k8  = (nk > k7 ) ? k7  : ((nk > k8 ) ? nk : k8 ); \
    k7  = (nk > k6 ) ? k6  : ((nk > k7 ) ? nk : k7 ); \
    k6  = (nk > k5 ) ? k5  : ((nk > k6 ) ? nk : k6 ); \
    k5  = (nk > k4 ) ? k4  : ((nk > k5 ) ? nk : k5 ); \
    k4  = (nk > k3 ) ? k3  : ((nk > k4 ) ? nk : k4 ); \
    k3  = (nk > k2 ) ? k2  : ((nk > k3 ) ? nk : k3 ); \
    k2  = (nk > k1 ) ? k1  : ((nk > k2 ) ? nk : k2 ); \
    k1  = (nk > k0 ) ? k0  : ((nk > k1 ) ? nk : k1 ); \
    k0  = (nk > k0 ) ? nk  : k0; \
} } while (0)

#define QPROC(pp, cidx) do { \
    float dx_ = qp.x - (pp).x, dy_ = qp.y - (pp).y, dz_ = qp.z - (pp).z; \
    float dd_ = dx_ * dx_; dd_ += dy_ * dy_; dd_ += dz_ * dz_; \
    if (dd_ < thr) { if (cnt < SCAP) surv[cnt][tid] = (unsigned short)(cidx); ++cnt; } \
} while (0)

__global__ __launch_bounds__(256) void knn_pair_kernel(const float4* __restrict__ pts,
        const int* __restrict__ perm, const float* __restrict__ thrbuf,
        long long* __restrict__ partK) {
    __shared__ unsigned short surv[SCAP][256];        // 16 KB, own-column, conflict-free
    __shared__ long long kbuf[128][17];               // 17.4 KB (+1 pad vs bank alias)
    const int pair = blockIdx.x, sg = blockIdx.y, b = blockIdx.z;
    const int tid = threadIdx.x;
    const int half = tid >> 7;                        // 0: chunk 2p, 1: chunk 2p+1
    const int lane = tid & 127;
    const int s = sg * 128 + lane;
    const int bs = b * SN + s;
    const float4* pb = pts + b * PN;
    const int chunk = 2 * pair + half;
    const int pbase = chunk * SCANCH;
    const float4 qp = pb[perm[bs]];
    const float thr = thrbuf[bs];
    int cnt = 0;
    const float4* cp = pb + pbase;
    // ---- phase A: 8-wide pipelined scan -> LDS survivor queue ----
    float4 a0 = cp[0], a1 = cp[1], a2 = cp[2], a3 = cp[3];
    float4 a4 = cp[4], a5 = cp[5], a6 = cp[6], a7 = cp[7];
    int c = 0;
    for (; c < SCANCH - 8; c += 8) {
        float4 n0 = cp[c + 8],  n1 = cp[c + 9],  n2 = cp[c + 10], n3 = cp[c + 11];
        float4 n4 = cp[c + 12], n5 = cp[c + 13], n6 = cp[c + 14], n7 = cp[c + 15];
        QPROC(a0, pbase + c + 0);
        QPROC(a1, pbase + c + 1);
        QPROC(a2, pbase + c + 2);
        QPROC(a3, pbase + c + 3);
        QPROC(a4, pbase + c + 4);
        QPROC(a5, pbase + c + 5);
        QPROC(a6, pbase + c + 6);
        QPROC(a7, pbase + c + 7);
        a0 = n0; a1 = n1; a2 = n2; a3 = n3;
        a4 = n4; a5 = n5; a6 = n6; a7 = n7;
    }
    QPROC(a0, pbase + c + 0);
    QPROC(a1, pbase + c + 1);
    QPROC(a2, pbase + c + 2);
    QPROC(a3, pbase + c + 3);
    QPROC(a4, pbase + c + 4);
    QPROC(a5, pbase + c + 5);
    QPROC(a6, pbase + c + 6);
    QPROC(a7, pbase + c + 7);
    // ---- phase B: exact f64 keys over survivors (own LDS column, warm) ----
    const double qx = qp.x, qy = qp.y, qz = qp.z;
    long long k0 = KEY_SENTINEL, k1 = KEY_SENTINEL, k2 = KEY_SENTINEL, k3 = KEY_SENTINEL,
              k4 = KEY_SENTINEL, k5 = KEY_SENTINEL, k6 = KEY_SENTINEL, k7 = KEY_SENTINEL,
              k8 = KEY_SENTINEL, k9 = KEY_SENTINEL, k10 = KEY_SENTINEL, k11 = KEY_SENTINEL,
              k12 = KEY_SENTINEL, k13 = KEY_SENTINEL, k14 = KEY_SENTINEL, k15 = KEY_SENTINEL;
    if (cnt <= SCAP) {
        for (int u = 0; u < cnt; u += 4) {
            int c0i = surv[u][tid];
            int c1i = (u + 1 < cnt) ? (int)surv[u + 1][tid] : 0;
            int c2i = (u + 2 < cnt) ? (int)surv[u + 2][tid] : 0;
            int c3i = (u + 3 < cnt) ? (int)surv[u + 3][tid] : 0;
            float4 p0 = pb[c0i], p1 = pb[c1i], p2 = pb[c2i], p3 = pb[c3i];  // warm L2
            long long kk0, kk1, kk2, kk3;
            MAKEKEY(p0, c0i, kk0);
            MAKEKEY(p1, c1i, kk1);
            MAKEKEY(p2, c2i, kk2);
            MAKEKEY(p3, c3i, kk3);
            kk1 = (u + 1 < cnt) ? kk1 : KEY_SENTINEL;
            kk2 = (u + 2 < cnt) ? kk2 : KEY_SENTINEL;
            kk3 = (u + 3 < cnt) ? kk3 : KEY_SENTINEL;
            INS16(kk0);
            INS16(kk1);
            INS16(kk2);
            INS16(kk3);
        }
    } else {
        // deterministic exact fallback (P ~ 3e-7 over all segments): rescan own chunk
        for (int cc = 0; cc < SCANCH; ++cc) {
            float4 pp = cp[cc];
            long long kk;
            MAKEKEY(pp, pbase + cc, kk);
            INS16(kk);
        }
    }
    // ---- pair-merge: upper half posts its sorted-16, lower half folds it in ----
    if (half) {
        kbuf[lane][0]  = k0;  kbuf[lane][1]  = k1;  kbuf[lane][2]  = k2;  kbuf[lane][3]  = k3;
        kbuf[lane][4]  = k4;  kbuf[lane][5]  = k5;  kbuf[lane][6]  = k6;  kbuf[lane][7]  = k7;
        kbuf[lane][8]  = k8;  kbuf[lane][9]  = k9;  kbuf[lane][10] = k10; kbuf[lane][11] = k11;
        kbuf[lane][12] = k12; kbuf[lane][13] = k13; kbuf[lane][14] = k14; kbuf[lane][15] = k15;
    }
    __syncthreads();
    if (!half) {
#pragma unroll
        for (int r = 0; r < 16; ++r) INS16(kbuf[lane][r]);
        long long* ok = partK + ((size_t)(b * NPAIR + pair) * SN + s) * KNB;
        ok[0]  = k0;  ok[1]  = k1;  ok[2]  = k2;  ok[3]  = k3;
        ok[4]  = k4;  ok[5]  = k5;  ok[6]  = k6;  ok[7]  = k7;
        ok[8]  = k8;  ok[9]  = k9;  ok[10] = k10; ok[11] = k11;
        ok[12] = k12; ok[13] = k13; ok[14] = k14; ok[15] = k15;
    }
}

// ---------------- K3: merge 4 sorted pair-lists, write knn[b][rank][s] ----------------
// Keys are unique (index embedded) except sentinels; pop-max 4-way merge, deterministic.
__global__ void knn_merge_kernel(const long long* __restrict__ partK, int* __restrict__ knn) {
    int t = blockIdx.x * 64 + threadIdx.x;            // 0 .. 2*SN-1, 256 blocks
    int b = t >> 13, s = t & (SN - 1);
    const long long* K0 = partK + ((size_t)(b * NPAIR + 0) * SN + s) * KNB;
    const long long* K1 = partK + ((size_t)(b * NPAIR + 1) * SN + s) * KNB;
    const long long* K2 = partK + ((size_t)(b * NPAIR + 2) * SN + s) * KNB;
    const long long* K3 = partK + ((size_t)(b * NPAIR + 3) * SN + s) * KNB;
    long long h0 = K0[0], h1 = K1[0], h2 = K2[0], h3 = K3[0];
    int p0 = 1, p1 = 1, p2 = 1, p3 = 1;
    int* ob = knn + (size_t)b * (SN * KNB);
    for (int r = 0; r < KNB; ++r) {
        long long m01 = h0 > h1 ? h0 : h1;
        long long m23 = h2 > h3 ? h2 : h3;
        long long m = m01 > m23 ? m01 : m23;
        ob[(size_t)r * SN + s] = 8191 - (int)(m & 8191);
        if (m == h0)      { h0 = (p0 < KNB) ? K0[p0] : KEY_SENTINEL; ++p0; }
        else if (m == h1) { h1 = (p1 < KNB) ? K1[p1] : KEY_SENTINEL; ++p1; }
        else if (m == h2) { h2 = (p2 < KNB) ? K2[p2] : KEY_SENTINEL; ++p2; }
        else              { h3 = (p3 < KNB) ? K3[p3] : KEY_SENTINEL; ++p3; }
    }
}

// ---------------- kernel 4: GroupNorm statistics ----------------
__global__ __launch_bounds__(256) void stats_kernel(const float* __restrict__ x,
        const int* __restrict__ knn, const float* __restrict__ w_pe,
        const float* __restrict__ w_conv, float* __restrict__ wavepart) {
    const int blk = blockIdx.x;                       // 0..255
    const int b = blockIdx.y;
    const int w = threadIdx.x >> 6, l = threadIdx.x & 63;
    float wr[10];
#pragma unroll
    for (int c = 0; c < 10; ++c) wr[c] = 0.f;
    if (l < 32) {
#pragma unroll
        for (int c = 0; c < 4; ++c) wr[c] = w_conv[l * 4 + c];
    } else {
#pragma unroll
        for (int c = 0; c < 10; ++c) wr[c] = w_pe[(l - 32) * 10 + c];
    }
    const float* xb = x + (size_t)b * 4 * PN;
    const int* kb = knn + (size_t)b * (SN * KNB);
    float s1 = 0.f, s2 = 0.f;
    const int nbase = blk * 512 + w * 128;
#pragma unroll 2
    for (int it = 0; it < 128; ++it) {
        int n = nbase + it;
        int i  = kb[n];
        int i0 = kb[n & ~15];
        float xa0 = xb[i], xa1 = xb[PN + i], xa2 = xb[2 * PN + i], xa3 = xb[3 * PN + i];
        float xc0 = xb[i0], xc1 = xb[PN + i0], xc2 = xb[2 * PN + i0];
        float d0 = xa0 - xc0, d1 = xa1 - xc1, d2 = xa2 - xc2;
        float dd = d0 * d0; dd += d1 * d1; dd += d2 * d2;
        float temp = sqrtf(fmaxf(dd, 1e-12f));
        float r;
        if (l < 32) {
            r = wr[0] * xa0 + wr[1] * xa1 + wr[2] * xa2 + wr[3] * xa3;
        } else {
            r = wr[0] * xa0 + wr[1] * xa1 + wr[2] * xa2
              + wr[3] * xc0 + wr[4] * xc1 + wr[5] * xc2
              + wr[6] * d0 + wr[7] * d1 + wr[8] * d2 + wr[9] * temp;
        }
        s1 += r;
        s2 += r * r;
    }
    const int wslot = blk * 4 + w;                    // 0..1023
    wavepart[((size_t)b * 1024 + wslot) * 128 + l] = s1;
    wavepart[((size_t)b * 1024 + wslot) * 128 + 64 + l] = s2;
}

// ---------------- kernel 5: finalize stats -> per-channel scale/shift ----------------
__global__ void finalize_kernel(const float* __restrict__ wavepart,
        const float* __restrict__ g_pe, const float* __restrict__ b_pe,
        const float* __restrict__ g_conv, const float* __restrict__ b_conv,
        float* __restrict__ scsh) {
    const int t = threadIdx.x;                        // 0..255
    const int b = t >> 7, k = t & 127;
    float acc = 0.f;
    for (int w = 0; w < 1024; ++w) acc += wavepart[((size_t)b * 1024 + w) * 128 + k];
    __shared__ float sums[2][128];
    sums[b][k] = acc;
    __syncthreads();
    if (k < 64) {
        const float N = 131072.f;
        float mean = sums[b][k] / N;
        float var = sums[b][64 + k] / N - mean * mean;
        float rstd = 1.0f / sqrtf(var + 1e-5f);
        float gam = (k < 32) ? g_conv[k] : g_pe[k - 32];
        float bet = (k < 32) ? b_conv[k] : b_pe[k - 32];
        float sc = gam * rstd;
        scsh[(b * 64 + k) * 2 + 0] = sc;
        scsh[(b * 64 + k) * 2 + 1] = bet - mean * sc;
    }
}

// ---------------- kernel 6: fused feature/attention/output ----------------
__global__ __launch_bounds__(256) void fused_main_kernel(
        const float* __restrict__ x, const int* __restrict__ knn,
        const float* __restrict__ w_pe, const float* __restrict__ w_conv,
        const float* __restrict__ w_att1, const float* __restrict__ w_att2,
        const float* __restrict__ w_b1, const float* __restrict__ w_b2,
        const float* __restrict__ scsh, float* __restrict__ out) {
    __shared__ float wb1T[64 * 64];                   // [c][o]
    __shared__ float wb2T[4 * 64];                    // [c][o]
    for (int i = threadIdx.x; i < 64 * 64; i += 256) wb1T[(i & 63) * 64 + (i >> 6)] = w_b1[i];
    { int i = threadIdx.x; wb2T[(i & 3) * 64 + (i >> 2)] = w_b2[i]; }
    __syncthreads();
    const int gidx = blockIdx.x;                      // 0..1023
    const int b = gidx >> 9;
    const int sb = (gidx & 511) << 4;
    const int l = threadIdx.x & 63;
    const int w = threadIdx.x >> 6;
    const int g = l >> 4, j = l & 15;
    const int s = sb + (w << 2) + g;
    const int srcl = g << 4;
    const float* xb = x + (size_t)b * 4 * PN;
    const int i1 = knn[(size_t)b * (SN * KNB) + (size_t)s * KNB + j];
    float xa0 = xb[i1], xa1 = xb[PN + i1], xa2 = xb[2 * PN + i1], xa3 = xb[3 * PN + i1];
    float xc0 = __shfl(xa0, srcl), xc1 = __shfl(xa1, srcl);
    float xc2 = __shfl(xa2, srcl), xc3 = __shfl(xa3, srcl);
    float d0 = xa0 - xc0, d1 = xa1 - xc1, d2 = xa2 - xc2;
    float dd = d0 * d0; dd += d1 * d1; dd += d2 * d2;
    float temp = sqrtf(fmaxf(dd, 1e-12f));
    float pem[10] = {xa0, xa1, xa2, xc0, xc1, xc2, d0, d1, d2, temp};
    float f[64];
    const float* ssb = scsh + b * 128;
#pragma unroll
    for (int o = 0; o < 32; ++o) {
        float r = w_conv[o * 4 + 0] * xa0;
        r += w_conv[o * 4 + 1] * xa1;
        r += w_conv[o * 4 + 2] * xa2;
        r += w_conv[o * 4 + 3] * xa3;
        r = r * ssb[o * 2 + 0] + ssb[o * 2 + 1];
        f[o] = (r >= 0.f) ? r : 0.2f * r;
    }
#pragma unroll
    for (int o = 0; o < 32; ++o) {
        float r = 0.f;
#pragma unroll
        for (int c = 0; c < 10; ++c) r += w_pe[o * 10 + c] * pem[c];
        r = r * ssb[(32 + o) * 2 + 0] + ssb[(32 + o) * 2 + 1];
        f[32 + o] = (r >= 0.f) ? r : 0.2f * r;
    }
    float logit = 0.f;
#pragma unroll 2
    for (int o = 0; o < 32; ++o) {
        float a = 0.f;
#pragma unroll
        for (int c = 0; c < 64; ++c) a += w_att1[o * 64 + c] * f[c];
        a = (a >= 0.f) ? a : 0.2f * a;
        logit += w_att2[o] * a;
    }
    float mx = logit;
    mx = fmaxf(mx, __shfl_xor(mx, 1));
    mx = fmaxf(mx, __shfl_xor(mx, 2));
    mx = fmaxf(mx, __shfl_xor(mx, 4));
    mx = fmaxf(mx, __shfl_xor(mx, 8));
    float e = expf(logit - mx);
    float se = e;
    se += __shfl_xor(se, 1);
    se += __shfl_xor(se, 2);
    se += __shfl_xor(se, 4);
    se += __shfl_xor(se, 8);
    float att = e / se;
#pragma unroll
    for (int c = 0; c < 64; ++c) {
        float v = f[c] * att;
        v += __shfl_xor(v, 1);
        v += __shfl_xor(v, 2);
        v += __shfl_xor(v, 4);
        v += __shfl_xor(v, 8);
        f[c] = v;
    }
    float o0 = 0.f, o1 = 0.f, o2 = 0.f, o3 = 0.f;
#pragma unroll
    for (int c = 0; c < 64; ++c) {
        float4 wv = *reinterpret_cast<const float4*>(&wb1T[c * 64 + 4 * j]);
        o0 += wv.x * f[c]; o1 += wv.y * f[c]; o2 += wv.z * f[c]; o3 += wv.w * f[c];
    }
    {
        float4 wv = *reinterpret_cast<const float4*>(&wb2T[0 * 64 + 4 * j]);
        o0 += wv.x * xc0; o1 += wv.y * xc0; o2 += wv.z * xc0; o3 += wv.w * xc0;
        wv = *reinterpret_cast<const float4*>(&wb2T[1 * 64 + 4 * j]);
        o0 += wv.x * xc1; o1 += wv.y * xc1; o2 += wv.z * xc1; o3 += wv.w * xc1;
        wv = *reinterpret_cast<const float4*>(&wb2T[2 * 64 + 4 * j]);
        o0 += wv.x * xc2; o1 += wv.y * xc2; o2 += wv.z * xc2; o3 += wv.w * xc2;
        wv = *reinterpret_cast<const float4*>(&wb2T[3 * 64 + 4 * j]);
        o0 += wv.x * xc3; o1 += wv.y * xc3; o2 += wv.z * xc3; o3 += wv.w * xc3;
    }
    o0 = (o0 >= 0.f) ? o0 : 0.1f * o0;
    o1 = (o1 >= 0.f) ? o1 : 0.1f * o1;
    o2 = (o2 >= 0.f) ? o2 : 0.1f * o2;
    o3 = (o3 >= 0.f) ? o3 : 0.1f * o3;
    float* ob = out + (size_t)b * 67 * SN;
    const int oc = 3 + 4 * j;
    ob[(size_t)(oc + 0) * SN + s] = o0;
    ob[(size_t)(oc + 1) * SN + s] = o1;
    ob[(size_t)(oc + 2) * SN + s] = o2;
    ob[(size_t)(oc + 3) * SN + s] = o3;
    if (j < 3) ob[(size_t)j * SN + s] = (j == 0) ? xc0 : ((j == 1) ? xc1 : xc2);
}

extern "C" void kernel_launch(void* const* d_in, const int* in_sizes, int n_in,
                              void* d_out, int out_size, void* d_ws, size_t ws_size,
                              hipStream_t stream) {
    (void)in_sizes; (void)n_in; (void)out_size; (void)ws_size;
    const float* x      = (const float*)d_in[0];
    const float* rnd    = (const float*)d_in[1];
    const float* w_pe   = (const float*)d_in[2];
    const float* g_pe   = (const float*)d_in[3];
    const float* b_pe   = (const float*)d_in[4];
    const float* w_conv = (const float*)d_in[5];
    const float* g_conv = (const float*)d_in[6];
    const float* b_conv = (const float*)d_in[7];
    const float* w_att1 = (const float*)d_in[8];
    const float* w_att2 = (const float*)d_in[9];
    const float* w_b1   = (const float*)d_in[10];
    const float* w_b2   = (const float*)d_in[11];
    float* out = (float*)d_out;
    char* ws = (char*)d_ws;
    // workspace carve-up (bytes), peak ~10.09 MB (< proven 10.81 MB).
    // Region A [327680, 8716288) = 8 MB, time-shared sequentially:
    //   rcnt (256K; rank_count->scatter) -> vv (8MB; K1->K1.5)
    //   -> partK (8MB exactly; knn_pair->merge) -> wavept (1MB; stats->finalize)
    float4*         pts    = (float4*)        (ws + 0);          //   262,144
    int*            perm   = (int*)           (ws + 262144);     //    65,536
    unsigned short* rcnt   = (unsigned short*)(ws + 327680);     //   262,144 (A)
    float*          vv     = (float*)         (ws + 327680);     // 8,388,608 (A)
    long long*      partK  = (long long*)     (ws + 327680);     // 8,388,608 (A) 16384*4*16*8
    float*          wavept = (float*)         (ws + 327680);     // 1,048,576 (A)
    float*          thrbuf = (float*)         (ws + 8716288);    //    65,536
    int*            knn    = (int*)           (ws + 9043968);    // 1,048,576
    float*          scsh   = (float*)         (ws + 10092544);   //     1,024

    pack_pts_kernel<<<64, 256, 0, stream>>>(x, pts);
    rank_count_kernel<<<dim3(NRCH, 32, 2), 256, 0, stream>>>(rnd, rcnt);
    rank_scatter_kernel<<<64, 256, 0, stream>>>(rcnt, perm);
    knn_val16_kernel<<<dim3(NCH1, 32, 2), 256, 0, stream>>>(pts, perm, vv);
    knn_thr_kernel<<<64, 256, 0, stream>>>(vv, thrbuf);
    knn_pair_kernel<<<dim3(NPAIR, 64, 2), 256, 0, stream>>>(pts, perm, thrbuf, partK);
    knn_merge_kernel<<<256, 64, 0, stream>>>(partK, knn);
    stats_kernel<<<dim3(256, 2), 256, 0, stream>>>(x, knn, w_pe, w_conv, wavept);
    finalize_kernel<<<1, 256, 0, stream>>>(wavept, g_pe, b_pe, g_conv, b_conv, scsh);
    fused_main_kernel<<<1024, 256, 0, stream>>>(x, knn, w_pe, w_conv, w_att1, w_att2,
                                                w_b1, w_b2, scsh, out);
}

// Round 17
// 287.833 us; speedup vs baseline: 1.3843x; 1.0674x over previous
//
#include <hip/hip_runtime.h>
#include <stdint.h>

#define PN 8192
#define SN 8192
#define KNB 16
#define SUBS 4                 // threshold subsample stride -> 2048 candidates
#define NCH1 8
#define CHUNK1 256             // subsample candidates per chunk
#define NSCAN 8                // scan chunks of 1024
#define SCANCH (PN / NSCAN)    // 1024
#define NPAIR 4                // output chunk-pairs (partK stays 8 MB)
#define SCAP 32                // per-(sample,1024-chunk) survivors: lambda=8, P(>32)~2e-12
#define MARGIN 1.0e-3f
#define NRCH 8
#define RCH (PN / NRCH)        // 1024

#define KEY_SENTINEL ((long long)0x8000000000000000ULL)
#define PD_SCALE 2199023255552.0   // 2^41: dd<1024 -> |scaled|<2^51; <<13 fits i64

// ---------------- helpers: branch-free sorted-16 maintenance ----------------
__device__ __forceinline__ void bitonic_sort16(float* b) {
#pragma unroll
    for (int k = 2; k <= 16; k <<= 1) {
#pragma unroll
        for (int j = k >> 1; j > 0; j >>= 1) {
#pragma unroll
            for (int i = 0; i < 16; ++i) {
                int l = i ^ j;
                if (l > i) {
                    float lo = fminf(b[i], b[l]), hi = fmaxf(b[i], b[l]);
                    bool up = ((i & k) == 0);
                    b[i] = up ? lo : hi;
                    b[l] = up ? hi : lo;
                }
            }
        }
    }
}
// r, b ascending sorted-16 -> r = lowest 16 of union, ascending.
__device__ __forceinline__ void merge16(float* r, const float* b) {
    float t[16];
#pragma unroll
    for (int i = 0; i < 16; ++i) t[i] = fminf(r[i], b[15 - i]);   // bitonic
#pragma unroll
    for (int j = 8; j > 0; j >>= 1) {
#pragma unroll
        for (int i = 0; i < 16; ++i) {
            int l = i ^ j;
            if (l > i) {
                float lo = fminf(t[i], t[l]), hi = fmaxf(t[i], t[l]);
                t[i] = lo; t[l] = hi;
            }
        }
    }
#pragma unroll
    for (int i = 0; i < 16; ++i) r[i] = t[i];
}

// ---------------- kernel 0: pack points (x,y,z,0) ----------------
__global__ void pack_pts_kernel(const float* __restrict__ x, float4* __restrict__ pts) {
    int i = blockIdx.x * 256 + threadIdx.x;           // 0 .. 2*PN-1
    int b = i >> 13, p = i & (PN - 1);
    const float* xb = x + (size_t)b * 4 * PN;
    pts[i] = make_float4(xb[p], xb[PN + p], xb[2 * PN + p], 0.f);
}

// ---------------- argsort stage A: partial rank counts (rank-by-counting) ----------------
__global__ __launch_bounds__(256) void rank_count_kernel(const float* __restrict__ rnd,
        unsigned short* __restrict__ rcnt) {
    __shared__ unsigned long long lk[RCH];            // 8 KB
    const int chunk = blockIdx.x, sg = blockIdx.y, b = blockIdx.z;
    const unsigned int* rb = (const unsigned int*)rnd + b * PN;   // [0,1) floats: bits order-preserving
    const int cbase = chunk * RCH;
    for (int c = threadIdx.x; c < RCH; c += 256) {
        int j = cbase + c;
        lk[c] = ((unsigned long long)rb[j] << 13) | (unsigned)j;
    }
    __syncthreads();
    const int i = sg * 256 + threadIdx.x;
    const unsigned long long ki = ((unsigned long long)rb[i] << 13) | (unsigned)i;
    int cnt = 0;
#pragma unroll 8
    for (int c = 0; c < RCH; ++c) cnt += (lk[c] < ki) ? 1 : 0;
    rcnt[(((size_t)(b * NRCH + chunk)) << 13) + i] = (unsigned short)cnt;
}

// ---------------- argsort stage B: sum partials, scatter perm[rank] = i ----------------
__global__ void rank_scatter_kernel(const unsigned short* __restrict__ rcnt,
                                    int* __restrict__ perm) {
    int t = blockIdx.x * 256 + threadIdx.x;           // 0 .. 2*PN-1
    int b = t >> 13, i = t & (PN - 1);
    int rank = 0;
#pragma unroll
    for (int ch = 0; ch < NRCH; ++ch)
        rank += rcnt[(((size_t)(b * NRCH + ch)) << 13) + i];
    perm[b * PN + rank] = i;
}

// ---------------- K1: per-(sample, subsample-chunk) sorted f32 top-16 distances ----------------
// Candidate stream is wave-uniform -> read straight from global (scalar-load path).
// Stride-4 SUBSAMPLE: subset's 16th order stat >= true d16.
__global__ __launch_bounds__(256) void knn_val16_kernel(const float4* __restrict__ pts,
        const int* __restrict__ perm, float* __restrict__ vv) {
    const int chunk = blockIdx.x, sg = blockIdx.y, b = blockIdx.z;
    const float4* pb = pts + b * PN;
    const int pbase = chunk * CHUNK1;
    const int s = sg * 256 + threadIdx.x;
    const float4 qp = pb[perm[b * PN + s]];
    float r[16];
#pragma unroll
    for (int i = 0; i < 16; ++i) r[i] = 3.0e38f;
    for (int t = 0; t < CHUNK1; t += 16) {
        float bv[16];
#pragma unroll
        for (int u = 0; u < 16; ++u) {
            float4 pp = pb[SUBS * (pbase + t + u)];   // uniform addr -> s_load
            float dx = qp.x - pp.x, dy = qp.y - pp.y, dz = qp.z - pp.z;
            bv[u] = dx * dx + dy * dy + dz * dz;
        }
        bitonic_sort16(bv);
        merge16(r, bv);
    }
    float* ov = vv + ((size_t)(b * NCH1 + chunk) * 16) * SN + s;
#pragma unroll
    for (int i = 0; i < 16; ++i) ov[(size_t)i * SN] = r[i];
}

// ---------------- K1.5: merge 8 sorted chunk value-lists -> subsample d16 -> thr ----------------
__global__ void knn_thr_kernel(const float* __restrict__ vv, float* __restrict__ thrbuf) {
    int t = blockIdx.x * 256 + threadIdx.x;           // 0 .. 2*SN-1
    int b = t >> 13, s = t & (SN - 1);
    float r[16], bl[16];
    const float* v0 = vv + ((size_t)(b * NCH1) * 16) * SN + s;
#pragma unroll
    for (int i = 0; i < 16; ++i) r[i] = v0[(size_t)i * SN];
    for (int ch = 1; ch < NCH1; ++ch) {
        const float* vc = vv + ((size_t)(b * NCH1 + ch) * 16) * SN + s;
#pragma unroll
        for (int i = 0; i < 16; ++i) bl[i] = vc[(size_t)i * SN];
        merge16(r, bl);
    }
    thrbuf[b * SN + s] = r[15] + MARGIN;              // >= true global d16 (subset bound)
}

// ---------------- K2: fused scan + exact top-16 per (sample, chunk-PAIR) ----------------
// Block = 128 samples x 2 chunks of 1024. Grid 512 blocks.
// Phase A: 8-wide pipelined scan with a BRANCH-FREE survivor append (round-16
// lesson: the conditional store's exec-mask branches blocked s_load pipelining,
// VALUBusy 41%): unconditionally store at slot min(cnt,SCAP-1); non-survivors
// are overwritten by the next survivor -> slots 0..cnt-1 are exactly the
// survivors in scan order. Overflow (cnt>SCAP) -> exact full rescan.
// Phase B: exact f64 keys via INS16 named-register network.
// Pair-merge: upper half posts sorted-16 via LDS (aliases surv; barrier first).
#define MAKEKEY(pp, c, out) do { \
    double dx_ = qx - (double)(pp).x; \
    double dy_ = qy - (double)(pp).y; \
    double dz_ = qz - (double)(pp).z; \
    double dd_ = dx_ * dx_ + dy_ * dy_ + dz_ * dz_; \
    long long sc_ = (long long)floor(-dd_ * PD_SCALE); \
    (out) = (sc_ << 13) | (long long)(8191 - (c)); \
} while (0)

#define INS16(kkv) do { long long nk = (kkv); if (nk > k15) { \
    k15 = (nk > k14) ? k14 : ((nk > k15) ? nk : k15); \
    k14 = (nk > k13) ? k13 : ((nk > k14) ? nk : k14); \
    k13 = (nk > k12) ? k12 : ((nk > k13) ? nk : k13); \
    k12 = (nk > k11) ? k11 : ((nk > k12) ? nk : k12); \
    k11 = (nk > k10) ? k10 : ((nk > k11) ? nk : k11); \
    k10 = (nk > k9 ) ? k9  : ((nk > k10) ? nk : k10); \
    k9  = (nk > k8 ) ? k8  : ((nk > k9 ) ? nk : k9 ); \
    k8  = (nk > k7 ) ? k7  : ((nk > k8 ) ? nk : k8 ); \
    k7  = (nk > k6 ) ? k6  : ((nk > k7 ) ? nk : k7 ); \
    k6  = (nk > k5 ) ? k5  : ((nk > k6 ) ? nk : k6 ); \
    k5  = (nk > k4 ) ? k4  : ((nk > k5 ) ? nk : k5 ); \
    k4  = (nk > k3 ) ? k3  : ((nk > k4 ) ? nk : k4 ); \
    k3  = (nk > k2 ) ? k2  : ((nk > k3 ) ? nk : k3 ); \
    k2  = (nk > k1 ) ? k1  : ((nk > k2 ) ? nk : k2 ); \
    k1  = (nk > k0 ) ? k0  : ((nk > k1 ) ? nk : k1 ); \
    k0  = (nk > k0 ) ? nk  : k0; \
} } while (0)

// branch-free append: unconditional store, predicated count
#define QPROC(pp, cidx) do { \
    float dx_ = qp.x - (pp).x, dy_ = qp.y - (pp).y, dz_ = qp.z - (pp).z; \
    float dd_ = dx_ * dx_; dd_ += dy_ * dy_; dd_ += dz_ * dz_; \
    int slot_ = (cnt < SCAP) ? cnt : (SCAP - 1); \
    surv[slot_][tid] = (unsigned short)(cidx); \
    cnt += (dd_ < thr) ? 1 : 0; \
} while (0)

__global__ __launch_bounds__(256) void knn_pair_kernel(const float4* __restrict__ pts,
        const int* __restrict__ perm, const float* __restrict__ thrbuf,
        long long* __restrict__ partK) {
    // 17.4 KB shared block, time-shared: surv (phase A/B) then kbuf (pair-merge)
    __shared__ __align__(16) char smem[128 * 17 * 8];
    unsigned short (*surv)[256] = (unsigned short (*)[256])smem;  // [SCAP][256] = 16 KB
    long long (*kbuf)[17] = (long long (*)[17])smem;              // [128][17] = 17.4 KB
    const int pair = blockIdx.x, sg = blockIdx.y, b = blockIdx.z;
    const int tid = threadIdx.x;
    const int half = tid >> 7;                        // 0: chunk 2p, 1: chunk 2p+1
    const int lane = tid & 127;
    const int s = sg * 128 + lane;
    const int bs = b * SN + s;
    const float4* pb = pts + b * PN;
    const int chunk = 2 * pair + half;
    const int pbase = chunk * SCANCH;
    const float4 qp = pb[perm[bs]];
    const float thr = thrbuf[bs];
    int cnt = 0;
    const float4* cp = pb + pbase;
    // ---- phase A: 8-wide pipelined branch-free scan -> LDS survivor queue ----
    float4 a0 = cp[0], a1 = cp[1], a2 = cp[2], a3 = cp[3];
    float4 a4 = cp[4], a5 = cp[5], a6 = cp[6], a7 = cp[7];
    int c = 0;
    for (; c < SCANCH - 8; c += 8) {
        float4 n0 = cp[c + 8],  n1 = cp[c + 9],  n2 = cp[c + 10], n3 = cp[c + 11];
        float4 n4 = cp[c + 12], n5 = cp[c + 13], n6 = cp[c + 14], n7 = cp[c + 15];
        QPROC(a0, pbase + c + 0);
        QPROC(a1, pbase + c + 1);
        QPROC(a2, pbase + c + 2);
        QPROC(a3, pbase + c + 3);
        QPROC(a4, pbase + c + 4);
        QPROC(a5, pbase + c + 5);
        QPROC(a6, pbase + c + 6);
        QPROC(a7, pbase + c + 7);
        a0 = n0; a1 = n1; a2 = n2; a3 = n3;
        a4 = n4; a5 = n5; a6 = n6; a7 = n7;
    }
    QPROC(a0, pbase + c + 0);
    QPROC(a1, pbase + c + 1);
    QPROC(a2, pbase + c + 2);
    QPROC(a3, pbase + c + 3);
    QPROC(a4, pbase + c + 4);
    QPROC(a5, pbase + c + 5);
    QPROC(a6, pbase + c + 6);
    QPROC(a7, pbase + c + 7);
    // ---- phase B: exact f64 keys over survivors (own LDS column, warm) ----
    const double qx = qp.x, qy = qp.y, qz = qp.z;
    long long k0 = KEY_SENTINEL, k1 = KEY_SENTINEL, k2 = KEY_SENTINEL, k3 = KEY_SENTINEL,
              k4 = KEY_SENTINEL, k5 = KEY_SENTINEL, k6 = KEY_SENTINEL, k7 = KEY_SENTINEL,
              k8 = KEY_SENTINEL, k9 = KEY_SENTINEL, k10 = KEY_SENTINEL, k11 = KEY_SENTINEL,
              k12 = KEY_SENTINEL, k13 = KEY_SENTINEL, k14 = KEY_SENTINEL, k15 = KEY_SENTINEL;
    if (cnt <= SCAP) {
        for (int u = 0; u < cnt; u += 4) {
            int c0i = surv[u][tid];
            int c1i = (u + 1 < cnt) ? (int)surv[u + 1][tid] : 0;
            int c2i = (u + 2 < cnt) ? (int)surv[u + 2][tid] : 0;
            int c3i = (u + 3 < cnt) ? (int)surv[u + 3][tid] : 0;
            float4 p0 = pb[c0i], p1 = pb[c1i], p2 = pb[c2i], p3 = pb[c3i];  // warm L2
            long long kk0, kk1, kk2, kk3;
            MAKEKEY(p0, c0i, kk0);
            MAKEKEY(p1, c1i, kk1);
            MAKEKEY(p2, c2i, kk2);
            MAKEKEY(p3, c3i, kk3);
            kk1 = (u + 1 < cnt) ? kk1 : KEY_SENTINEL;
            kk2 = (u + 2 < cnt) ? kk2 : KEY_SENTINEL;
            kk3 = (u + 3 < cnt) ? kk3 : KEY_SENTINEL;
            INS16(kk0);
            INS16(kk1);
            INS16(kk2);
            INS16(kk3);
        }
    } else {
        // deterministic exact fallback (P ~ 3e-7 over all segments): rescan own chunk
        for (int cc = 0; cc < SCANCH; ++cc) {
            float4 pp = cp[cc];
            long long kk;
            MAKEKEY(pp, pbase + cc, kk);
            INS16(kk);
        }
    }
    // ---- pair-merge (kbuf aliases surv: barrier before overwrite) ----
    __syncthreads();
    if (half) {
        kbuf[lane][0]  = k0;  kbuf[lane][1]  = k1;  kbuf[lane][2]  = k2;  kbuf[lane][3]  = k3;
        kbuf[lane][4]  = k4;  kbuf[lane][5]  = k5;  kbuf[lane][6]  = k6;  kbuf[lane][7]  = k7;
        kbuf[lane][8]  = k8;  kbuf[lane][9]  = k9;  kbuf[lane][10] = k10; kbuf[lane][11] = k11;
        kbuf[lane][12] = k12; kbuf[lane][13] = k13; kbuf[lane][14] = k14; kbuf[lane][15] = k15;
    }
    __syncthreads();
    if (!half) {
#pragma unroll
        for (int r = 0; r < 16; ++r) INS16(kbuf[lane][r]);
        long long* ok = partK + ((size_t)(b * NPAIR + pair) * SN + s) * KNB;
        ok[0]  = k0;  ok[1]  = k1;  ok[2]  = k2;  ok[3]  = k3;
        ok[4]  = k4;  ok[5]  = k5;  ok[6]  = k6;  ok[7]  = k7;
        ok[8]  = k8;  ok[9]  = k9;  ok[10] = k10; ok[11] = k11;
        ok[12] = k12; ok[13] = k13; ok[14] = k14; ok[15] = k15;
    }
}

// ---------------- K3: merge 4 sorted pair-lists, write knn[b][rank][s] ----------------
// Keys are unique (index embedded) except sentinels; pop-max 4-way merge, deterministic.
__global__ void knn_merge_kernel(const long long* __restrict__ partK, int* __restrict__ knn) {
    int t = blockIdx.x * 64 + threadIdx.x;            // 0 .. 2*SN-1, 256 blocks
    int b = t >> 13, s = t & (SN - 1);
    const long long* K0 = partK + ((size_t)(b * NPAIR + 0) * SN + s) * KNB;
    const long long* K1 = partK + ((size_t)(b * NPAIR + 1) * SN + s) * KNB;
    const long long* K2 = partK + ((size_t)(b * NPAIR + 2) * SN + s) * KNB;
    const long long* K3 = partK + ((size_t)(b * NPAIR + 3) * SN + s) * KNB;
    long long h0 = K0[0], h1 = K1[0], h2 = K2[0], h3 = K3[0];
    int p0 = 1, p1 = 1, p2 = 1, p3 = 1;
    int* ob = knn + (size_t)b * (SN * KNB);
    for (int r = 0; r < KNB; ++r) {
        long long m01 = h0 > h1 ? h0 : h1;
        long long m23 = h2 > h3 ? h2 : h3;
        long long m = m01 > m23 ? m01 : m23;
        ob[(size_t)r * SN + s] = 8191 - (int)(m & 8191);
        if (m == h0)      { h0 = (p0 < KNB) ? K0[p0] : KEY_SENTINEL; ++p0; }
        else if (m == h1) { h1 = (p1 < KNB) ? K1[p1] : KEY_SENTINEL; ++p1; }
        else if (m == h2) { h2 = (p2 < KNB) ? K2[p2] : KEY_SENTINEL; ++p2; }
        else              { h3 = (p3 < KNB) ? K3[p3] : KEY_SENTINEL; ++p3; }
    }
}

// ---------------- kernel 4: GroupNorm statistics ----------------
__global__ __launch_bounds__(256) void stats_kernel(const float* __restrict__ x,
        const int* __restrict__ knn, const float* __restrict__ w_pe,
        const float* __restrict__ w_conv, float* __restrict__ wavepart) {
    const int blk = blockIdx.x;                       // 0..255
    const int b = blockIdx.y;
    const int w = threadIdx.x >> 6, l = threadIdx.x & 63;
    float wr[10];
#pragma unroll
    for (int c = 0; c < 10; ++c) wr[c] = 0.f;
    if (l < 32) {
#pragma unroll
        for (int c = 0; c < 4; ++c) wr[c] = w_conv[l * 4 + c];
    } else {
#pragma unroll
        for (int c = 0; c < 10; ++c) wr[c] = w_pe[(l - 32) * 10 + c];
    }
    const float* xb = x + (size_t)b * 4 * PN;
    const int* kb = knn + (size_t)b * (SN * KNB);
    float s1 = 0.f, s2 = 0.f;
    const int nbase = blk * 512 + w * 128;
#pragma unroll 2
    for (int it = 0; it < 128; ++it) {
        int n = nbase + it;
        int i  = kb[n];
        int i0 = kb[n & ~15];
        float xa0 = xb[i], xa1 = xb[PN + i], xa2 = xb[2 * PN + i], xa3 = xb[3 * PN + i];
        float xc0 = xb[i0], xc1 = xb[PN + i0], xc2 = xb[2 * PN + i0];
        float d0 = xa0 - xc0, d1 = xa1 - xc1, d2 = xa2 - xc2;
        float dd = d0 * d0; dd += d1 * d1; dd += d2 * d2;
        float temp = sqrtf(fmaxf(dd, 1e-12f));
        float r;
        if (l < 32) {
            r = wr[0] * xa0 + wr[1] * xa1 + wr[2] * xa2 + wr[3] * xa3;
        } else {
            r = wr[0] * xa0 + wr[1] * xa1 + wr[2] * xa2
              + wr[3] * xc0 + wr[4] * xc1 + wr[5] * xc2
              + wr[6] * d0 + wr[7] * d1 + wr[8] * d2 + wr[9] * temp;
        }
        s1 += r;
        s2 += r * r;
    }
    const int wslot = blk * 4 + w;                    // 0..1023
    wavepart[((size_t)b * 1024 + wslot) * 128 + l] = s1;
    wavepart[((size_t)b * 1024 + wslot) * 128 + 64 + l] = s2;
}

// ---------------- kernel 5: finalize stats -> per-channel scale/shift ----------------
__global__ void finalize_kernel(const float* __restrict__ wavepart,
        const float* __restrict__ g_pe, const float* __restrict__ b_pe,
        const float* __restrict__ g_conv, const float* __restrict__ b_conv,
        float* __restrict__ scsh) {
    const int t = threadIdx.x;                        // 0..255
    const int b = t >> 7, k = t & 127;
    float acc = 0.f;
    for (int w = 0; w < 1024; ++w) acc += wavepart[((size_t)b * 1024 + w) * 128 + k];
    __shared__ float sums[2][128];
    sums[b][k] = acc;
    __syncthreads();
    if (k < 64) {
        const float N = 131072.f;
        float mean = sums[b][k] / N;
        float var = sums[b][64 + k] / N - mean * mean;
        float rstd = 1.0f / sqrtf(var + 1e-5f);
        float gam = (k < 32) ? g_conv[k] : g_pe[k - 32];
        float bet = (k < 32) ? b_conv[k] : b_pe[k - 32];
        float sc = gam * rstd;
        scsh[(b * 64 + k) * 2 + 0] = sc;
        scsh[(b * 64 + k) * 2 + 1] = bet - mean * sc;
    }
}

// ---------------- kernel 6: fused feature/attention/output ----------------
__global__ __launch_bounds__(256) void fused_main_kernel(
        const float* __restrict__ x, const int* __restrict__ knn,
        const float* __restrict__ w_pe, const float* __restrict__ w_conv,
        const float* __restrict__ w_att1, const float* __restrict__ w_att2,
        const float* __restrict__ w_b1, const float* __restrict__ w_b2,
        const float* __restrict__ scsh, float* __restrict__ out) {
    __shared__ float wb1T[64 * 64];                   // [c][o]
    __shared__ float wb2T[4 * 64];                    // [c][o]
    for (int i = threadIdx.x; i < 64 * 64; i += 256) wb1T[(i & 63) * 64 + (i >> 6)] = w_b1[i];
    { int i = threadIdx.x; wb2T[(i & 3) * 64 + (i >> 2)] = w_b2[i]; }
    __syncthreads();
    const int gidx = blockIdx.x;                      // 0..1023
    const int b = gidx >> 9;
    const int sb = (gidx & 511) << 4;
    const int l = threadIdx.x & 63;
    const int w = threadIdx.x >> 6;
    const int g = l >> 4, j = l & 15;
    const int s = sb + (w << 2) + g;
    const int srcl = g << 4;
    const float* xb = x + (size_t)b * 4 * PN;
    const int i1 = knn[(size_t)b * (SN * KNB) + (size_t)s * KNB + j];
    float xa0 = xb[i1], xa1 = xb[PN + i1], xa2 = xb[2 * PN + i1], xa3 = xb[3 * PN + i1];
    float xc0 = __shfl(xa0, srcl), xc1 = __shfl(xa1, srcl);
    float xc2 = __shfl(xa2, srcl), xc3 = __shfl(xa3, srcl);
    float d0 = xa0 - xc0, d1 = xa1 - xc1, d2 = xa2 - xc2;
    float dd = d0 * d0; dd += d1 * d1; dd += d2 * d2;
    float temp = sqrtf(fmaxf(dd, 1e-12f));
    float pem[10] = {xa0, xa1, xa2, xc0, xc1, xc2, d0, d1, d2, temp};
    float f[64];
    const float* ssb = scsh + b * 128;
#pragma unroll
    for (int o = 0; o < 32; ++o) {
        float r = w_conv[o * 4 + 0] * xa0;
        r += w_conv[o * 4 + 1] * xa1;
        r += w_conv[o * 4 + 2] * xa2;
        r += w_conv[o * 4 + 3] * xa3;
        r = r * ssb[o * 2 + 0] + ssb[o * 2 + 1];
        f[o] = (r >= 0.f) ? r : 0.2f * r;
    }
#pragma unroll
    for (int o = 0; o < 32; ++o) {
        float r = 0.f;
#pragma unroll
        for (int c = 0; c < 10; ++c) r += w_pe[o * 10 + c] * pem[c];
        r = r * ssb[(32 + o) * 2 + 0] + ssb[(32 + o) * 2 + 1];
        f[32 + o] = (r >= 0.f) ? r : 0.2f * r;
    }
    float logit = 0.f;
#pragma unroll 2
    for (int o = 0; o < 32; ++o) {
        float a = 0.f;
#pragma unroll
        for (int c = 0; c < 64; ++c) a += w_att1[o * 64 + c] * f[c];
        a = (a >= 0.f) ? a : 0.2f * a;
        logit += w_att2[o] * a;
    }
    float mx = logit;
    mx = fmaxf(mx, __shfl_xor(mx, 1));
    mx = fmaxf(mx, __shfl_xor(mx, 2));
    mx = fmaxf(mx, __shfl_xor(mx, 4));
    mx = fmaxf(mx, __shfl_xor(mx, 8));
    float e = expf(logit - mx);
    float se = e;
    se += __shfl_xor(se, 1);
    se += __shfl_xor(se, 2);
    se += __shfl_xor(se, 4);
    se += __shfl_xor(se, 8);
    float att = e / se;
#pragma unroll
    for (int c = 0; c < 64; ++c) {
        float v = f[c] * att;
        v += __shfl_xor(v, 1);
        v += __shfl_xor(v, 2);
        v += __shfl_xor(v, 4);
        v += __shfl_xor(v, 8);
        f[c] = v;
    }
    float o0 = 0.f, o1 = 0.f, o2 = 0.f, o3 = 0.f;
#pragma unroll
    for (int c = 0; c < 64; ++c) {
        float4 wv = *reinterpret_cast<const float4*>(&wb1T[c * 64 + 4 * j]);
        o0 += wv.x * f[c]; o1 += wv.y * f[c]; o2 += wv.z * f[c]; o3 += wv.w * f[c];
    }
    {
        float4 wv = *reinterpret_cast<const float4*>(&wb2T[0 * 64 + 4 * j]);
        o0 += wv.x * xc0; o1 += wv.y * xc0; o2 += wv.z * xc0; o3 += wv.w * xc0;
        wv = *reinterpret_cast<const float4*>(&wb2T[1 * 64 + 4 * j]);
        o0 += wv.x * xc1; o1 += wv.y * xc1; o2 += wv.z * xc1; o3 += wv.w * xc1;
        wv = *reinterpret_cast<const float4*>(&wb2T[2 * 64 + 4 * j]);
        o0 += wv.x * xc2; o1 += wv.y * xc2; o2 += wv.z * xc2; o3 += wv.w * xc2;
        wv = *reinterpret_cast<const float4*>(&wb2T[3 * 64 + 4 * j]);
        o0 += wv.x * xc3; o1 += wv.y * xc3; o2 += wv.z * xc3; o3 += wv.w * xc3;
    }
    o0 = (o0 >= 0.f) ? o0 : 0.1f * o0;
    o1 = (o1 >= 0.f) ? o1 : 0.1f * o1;
    o2 = (o2 >= 0.f) ? o2 : 0.1f * o2;
    o3 = (o3 >= 0.f) ? o3 : 0.1f * o3;
    float* ob = out + (size_t)b * 67 * SN;
    const int oc = 3 + 4 * j;
    ob[(size_t)(oc + 0) * SN + s] = o0;
    ob[(size_t)(oc + 1) * SN + s] = o1;
    ob[(size_t)(oc + 2) * SN + s] = o2;
    ob[(size_t)(oc + 3) * SN + s] = o3;
    if (j < 3) ob[(size_t)j * SN + s] = (j == 0) ? xc0 : ((j == 1) ? xc1 : xc2);
}

extern "C" void kernel_launch(void* const* d_in, const int* in_sizes, int n_in,
                              void* d_out, int out_size, void* d_ws, size_t ws_size,
                              hipStream_t stream) {
    (void)in_sizes; (void)n_in; (void)out_size; (void)ws_size;
    const float* x      = (const float*)d_in[0];
    const float* rnd    = (const float*)d_in[1];
    const float* w_pe   = (const float*)d_in[2];
    const float* g_pe   = (const float*)d_in[3];
    const float* b_pe   = (const float*)d_in[4];
    const float* w_conv = (const float*)d_in[5];
    const float* g_conv = (const float*)d_in[6];
    const float* b_conv = (const float*)d_in[7];
    const float* w_att1 = (const float*)d_in[8];
    const float* w_att2 = (const float*)d_in[9];
    const float* w_b1   = (const float*)d_in[10];
    const float* w_b2   = (const float*)d_in[11];
    float* out = (float*)d_out;
    char* ws = (char*)d_ws;
    // workspace carve-up (bytes), peak ~10.09 MB (< proven 10.81 MB).
    // Region A [327680, 8716288) = 8 MB, time-shared sequentially:
    //   rcnt (256K; rank_count->scatter) -> vv (8MB; K1->K1.5)
    //   -> partK (8MB exactly; knn_pair->merge) -> wavept (1MB; stats->finalize)
    float4*         pts    = (float4*)        (ws + 0);          //   262,144
    int*            perm   = (int*)           (ws + 262144);     //    65,536
    unsigned short* rcnt   = (unsigned short*)(ws + 327680);     //   262,144 (A)
    float*          vv     = (float*)         (ws + 327680);     // 8,388,608 (A)
    long long*      partK  = (long long*)     (ws + 327680);     // 8,388,608 (A) 16384*4*16*8
    float*          wavept = (float*)         (ws + 327680);     // 1,048,576 (A)
    float*          thrbuf = (float*)         (ws + 8716288);    //    65,536
    int*            knn    = (int*)           (ws + 9043968);    // 1,048,576
    float*          scsh   = (float*)         (ws + 10092544);   //     1,024

    pack_pts_kernel<<<64, 256, 0, stream>>>(x, pts);
    rank_count_kernel<<<dim3(NRCH, 32, 2), 256, 0, stream>>>(rnd, rcnt);
    rank_scatter_kernel<<<64, 256, 0, stream>>>(rcnt, perm);
    knn_val16_kernel<<<dim3(NCH1, 32, 2), 256, 0, stream>>>(pts, perm, vv);
    knn_thr_kernel<<<64, 256, 0, stream>>>(vv, thrbuf);
    knn_pair_kernel<<<dim3(NPAIR, 64, 2), 256, 0, stream>>>(pts, perm, thrbuf, partK);
    knn_merge_kernel<<<256, 64, 0, stream>>>(partK, knn);
    stats_kernel<<<dim3(256, 2), 256, 0, stream>>>(x, knn, w_pe, w_conv, wavept);
    finalize_kernel<<<1, 256, 0, stream>>>(wavept, g_pe, b_pe, g_conv, b_conv, scsh);
    fused_main_kernel<<<1024, 256, 0, stream>>>(x, knn, w_pe, w_conv, w_att1, w_att2,
                                                w_b1, w_b2, scsh, out);
}